// Round 1
// baseline (897.447 us; speedup 1.0000x reference)
//
#include <hip/hip_runtime.h>

#define NN   4096
#define NQ   (NN*4)
#define QQ   4
#define LTT  8
#define DD   32
#define MM   128
#define SIG2 0.001f
#define JIT  1e-5f

// ---------------- per-n precompute ----------------
__global__ __launch_bounds__(256) void prep_kernel(
    const float* __restrict__ Xm, const float* __restrict__ Xv,
    const float* __restrict__ ls, const float* __restrict__ varp,
    float* __restrict__ a_g, float* __restrict__ axm_g, float* __restrict__ dinv_g,
    float* __restrict__ L1_g, float* __restrict__ base1_g)
{
    int n = blockIdx.x * 256 + threadIdx.x;
    float var = varp[0];
    float slog2 = 0.f, slog1 = 0.f, T1 = 0.f;
    for (int q = 0; q < DD; ++q) {
        float xm = Xm[n*QQ + q];
        float xv = Xv[n*QQ + q];
        float l  = ls[q];
        float l2 = l*l;
        float aq = 1.0f / (2.0f*xv + l2);
        a_g[n*DD + q]    = aq;
        axm_g[n*DD + q]  = aq * xm;
        dinv_g[n*DD + q] = 1.0f / (l2 + xv);
        slog2 += log1pf(2.0f*xv/l2);
        slog1 += log1pf(xv/l2);
        T1    += aq*xm*xm;
    }
    L1_g[n]    = 2.0f*logf(var) - 0.5f*slog2 - T1;   // log(cn) - T1
    base1_g[n] = logf(var) - 0.5f*slog1;             // log(var) + logdet1
}

// -------- psi1 (fused into Y = psi1^T @ X_mo), T2, T3 --------
__global__ __launch_bounds__(256) void k1_kernel(
    const float* __restrict__ Xm, const float* __restrict__ Zg,
    const float* __restrict__ a_g, const float* __restrict__ axm_g,
    const float* __restrict__ dinv_g, const float* __restrict__ base1_g,
    float* __restrict__ t2_g, float* __restrict__ t3_g, float* __restrict__ Yg)
{
    int n = blockIdx.x*256 + threadIdx.x;
    int m = blockIdx.y;
    float q1 = 0.f, t2v = 0.f, t3v = 0.f;
    for (int q = 0; q < DD; ++q) {
        float z    = Zg[m*DD+q];
        float xm   = Xm[n*QQ+q];
        float diff = xm - z;
        q1  += diff*diff*dinv_g[n*DD+q];
        t2v += axm_g[n*DD+q]*z;
        t3v += a_g[n*DD+q]*z*z;
    }
    t2_g[n*MM+m] = t2v;
    t3_g[n*MM+m] = t3v;
    float p1 = __expf(base1_g[n] - 0.5f*q1);   // psi1[n,m]
    #pragma unroll
    for (int c = 0; c < QQ; ++c) {
        float v = p1 * Xm[(LTT+n)*QQ + c];
        for (int off = 32; off; off >>= 1) v += __shfl_xor(v, off, 64);
        if ((threadIdx.x & 63) == 0) atomicAdd(&Yg[m*QQ+c], v);
    }
}

// ---------------- Kuu ----------------
__global__ __launch_bounds__(256) void kuu_kernel(
    const float* __restrict__ Zg, const float* __restrict__ ls,
    const float* __restrict__ varp, float* __restrict__ Kuu)
{
    int idx = blockIdx.x*256 + threadIdx.x;
    int i = idx >> 7, j = idx & 127;
    float var = varp[0];
    float s = 0.f;
    for (int q = 0; q < DD; ++q) {
        float l = ls[q];
        float d = (Zg[i*DD+q] - Zg[j*DD+q]) / l;
        s += d*d;
    }
    float v = var * expf(-0.5f*s);
    if (i == j) v += JIT;
    Kuu[idx] = v;
}

// ---------------- 128x128 Cholesky, single block ----------------
__global__ __launch_bounds__(256) void chol_kernel(const float* __restrict__ Ain,
                                                   float* __restrict__ Lout)
{
    __shared__ float mat[MM*129];
    int tid = threadIdx.x;
    for (int idx = tid; idx < MM*MM; idx += 256) {
        int i = idx >> 7, j = idx & 127;
        mat[i*129+j] = Ain[idx];
    }
    __syncthreads();
    int tx = tid & 15, ty = tid >> 4;
    for (int k = 0; k < MM; ++k) {
        float dk  = sqrtf(mat[k*129+k]);
        float rdk = 1.0f/dk;
        for (int i = k+1+tid; i < MM; i += 256) mat[i*129+k] *= rdk;
        __syncthreads();
        if (tid == 0) mat[k*129+k] = dk;
        for (int i = k+1+ty; i < MM; i += 16) {
            float lik = mat[i*129+k];
            for (int j = k+1+tx; j <= i; j += 16) mat[i*129+j] -= lik*mat[j*129+k];
        }
        __syncthreads();
    }
    for (int idx = tid; idx < MM*MM; idx += 256) {
        int i = idx >> 7, j = idx & 127;
        Lout[idx] = (j <= i) ? mat[i*129+j] : 0.f;
    }
}

// ------- lower-tri inverse, one wave per column -------
__global__ __launch_bounds__(64) void triinv_kernel(const float* __restrict__ Lg,
                                                    float* __restrict__ Xout)
{
    int c = blockIdx.x, lane = threadIdx.x;
    __shared__ float x[MM];
    if (lane == 0) x[c] = 1.0f / Lg[c*MM+c];
    __syncthreads();
    for (int i = c+1; i < MM; ++i) {
        float p = 0.f;
        for (int j = c+lane; j < i; j += 64) p += Lg[i*MM+j]*x[j];
        for (int off = 32; off; off >>= 1) p += __shfl_xor(p, off, 64);
        if (lane == 0) x[i] = -p / Lg[i*MM+i];
        __syncthreads();
    }
    for (int i = lane; i < MM; i += 64) Xout[i*MM+c] = (i < c) ? 0.f : x[i];
}

// ------- triangular solve, 4 RHS (one wave per column of Y) -------
__global__ __launch_bounds__(64) void trisolve_kernel(const float* __restrict__ Lg,
                                                      const float* __restrict__ Yg,
                                                      float* __restrict__ Wg)
{
    int c = blockIdx.x, lane = threadIdx.x;
    __shared__ float x[MM];
    for (int i = 0; i < MM; ++i) {
        float p = 0.f;
        for (int j = lane; j < i; j += 64) p += Lg[i*MM+j]*x[j];
        for (int off = 32; off; off >>= 1) p += __shfl_xor(p, off, 64);
        if (lane == 0) x[i] = (Yg[i*QQ+c] - p) / Lg[i*MM+i];
        __syncthreads();
    }
    for (int i = lane; i < MM; i += 64) Wg[i*QQ+c] = x[i];
}

// ---------------- psi2: the heavy contraction ----------------
__global__ __launch_bounds__(256) void psi2_kernel(
    const float* __restrict__ Zg, const float* __restrict__ ls,
    const float* __restrict__ a_g, const float* __restrict__ L1_g,
    const float* __restrict__ t2_g, const float* __restrict__ t3_g,
    float* __restrict__ psi2)
{
    __shared__ float Zm_l[64][33];
    __shared__ float Zk_l[64][33];
    __shared__ float invl2[DD];
    __shared__ float a_s[8][33];
    __shared__ float t2m_s[8][64];
    __shared__ float t2k_s[8][64];
    __shared__ float t3m_s[8][64];
    __shared__ float t3k_s[8][64];
    __shared__ float L1_s[8];
    int tid = threadIdx.x;
    int m0 = (blockIdx.x >> 1) * 64;
    int k0 = (blockIdx.x & 1) * 64;
    int n0 = blockIdx.y * 32;
    for (int idx = tid; idx < 64*DD; idx += 256) {
        int r = idx >> 5, q = idx & 31;
        Zm_l[r][q] = Zg[(m0+r)*DD+q];
        Zk_l[r][q] = Zg[(k0+r)*DD+q];
    }
    if (tid < DD) { float l = ls[tid]; invl2[tid] = 1.0f/(l*l); }
    __syncthreads();
    int tx = tid & 15, ty = tid >> 4;
    float dz2[4][4];
    #pragma unroll
    for (int im = 0; im < 4; ++im)
        #pragma unroll
        for (int ik = 0; ik < 4; ++ik) {
            float s = 0.f;
            for (int q = 0; q < DD; ++q) {
                float d = Zm_l[tx+16*im][q] - Zk_l[ty+16*ik][q];
                s += d*d*invl2[q];
            }
            dz2[im][ik] = 0.25f*s;
        }
    float acc[4][4];
    #pragma unroll
    for (int im = 0; im < 4; ++im)
        #pragma unroll
        for (int ik = 0; ik < 4; ++ik) acc[im][ik] = 0.f;

    for (int nb = 0; nb < 32; nb += 8) {
        __syncthreads();
        int nn0 = n0 + nb;
        { int i = tid >> 5, q = tid & 31; a_s[i][q] = a_g[(nn0+i)*DD+q]; }
        for (int idx = tid; idx < 512; idx += 256) { int i = idx>>6, j = idx&63; t2m_s[i][j] = t2_g[(nn0+i)*MM+m0+j]; }
        for (int idx = tid; idx < 512; idx += 256) { int i = idx>>6, j = idx&63; t2k_s[i][j] = t2_g[(nn0+i)*MM+k0+j]; }
        for (int idx = tid; idx < 512; idx += 256) { int i = idx>>6, j = idx&63; t3m_s[i][j] = t3_g[(nn0+i)*MM+m0+j]; }
        for (int idx = tid; idx < 512; idx += 256) { int i = idx>>6, j = idx&63; t3k_s[i][j] = t3_g[(nn0+i)*MM+k0+j]; }
        if (tid < 8) L1_s[tid] = L1_g[nn0+tid];
        __syncthreads();
        for (int i = 0; i < 8; ++i) {
            float t4[4][4];
            #pragma unroll
            for (int im = 0; im < 4; ++im)
                #pragma unroll
                for (int ik = 0; ik < 4; ++ik) t4[im][ik] = 0.f;
            #pragma unroll
            for (int q = 0; q < DD; ++q) {
                float aq = a_s[i][q];
                float p0 = aq*Zm_l[tx   ][q];
                float p1 = aq*Zm_l[tx+16][q];
                float p2 = aq*Zm_l[tx+32][q];
                float p3 = aq*Zm_l[tx+48][q];
                float z0 = Zk_l[ty   ][q];
                float z1 = Zk_l[ty+16][q];
                float z2 = Zk_l[ty+32][q];
                float z3 = Zk_l[ty+48][q];
                t4[0][0] += p0*z0; t4[0][1] += p0*z1; t4[0][2] += p0*z2; t4[0][3] += p0*z3;
                t4[1][0] += p1*z0; t4[1][1] += p1*z1; t4[1][2] += p1*z2; t4[1][3] += p1*z3;
                t4[2][0] += p2*z0; t4[2][1] += p2*z1; t4[2][2] += p2*z2; t4[2][3] += p2*z3;
                t4[3][0] += p3*z0; t4[3][1] += p3*z1; t4[3][2] += p3*z2; t4[3][3] += p3*z3;
            }
            float L1v = L1_s[i];
            float em[4], ek[4];
            #pragma unroll
            for (int im = 0; im < 4; ++im) em[im] = L1v + t2m_s[i][tx+16*im] - 0.25f*t3m_s[i][tx+16*im];
            #pragma unroll
            for (int ik = 0; ik < 4; ++ik) ek[ik] = t2k_s[i][ty+16*ik] - 0.25f*t3k_s[i][ty+16*ik];
            #pragma unroll
            for (int im = 0; im < 4; ++im)
                #pragma unroll
                for (int ik = 0; ik < 4; ++ik)
                    acc[im][ik] += __expf(em[im] + ek[ik] - 0.5f*t4[im][ik] - dz2[im][ik]);
        }
    }
    #pragma unroll
    for (int im = 0; im < 4; ++im)
        #pragma unroll
        for (int ik = 0; ik < 4; ++ik)
            atomicAdd(&psi2[(m0+tx+16*im)*MM + (k0+ty+16*ik)], acc[im][ik]);
}

// ---------------- G = Kuu + psi2/sigma2 ----------------
__global__ __launch_bounds__(256) void gadd_kernel(const float* __restrict__ Kuu,
                                                   const float* __restrict__ psi2,
                                                   float* __restrict__ G)
{
    int idx = blockIdx.x*256 + threadIdx.x;
    G[idx] = Kuu[idx] + (1.0f/SIG2)*psi2[idx];
}

// ---------------- tmp = Linv @ psi2 ----------------
__global__ __launch_bounds__(256) void tmpmul_kernel(const float* __restrict__ Linvg,
                                                     const float* __restrict__ psi2,
                                                     float* __restrict__ tmpg)
{
    int idx = blockIdx.x*256 + threadIdx.x;
    int i = idx >> 7, p = idx & 127;
    float s = 0.f;
    for (int j = 0; j < MM; ++j) s += Linvg[i*MM+j]*psi2[j*MM+p];
    tmpg[idx] = s;
}

// ---------------- scalar stats over X ----------------
__global__ __launch_bounds__(256) void stats_kernel(const float* __restrict__ Xm,
                                                    const float* __restrict__ Xv,
                                                    float* __restrict__ sums)
{
    int idx = blockIdx.x*256 + threadIdx.x;   // 0..16383
    float mo = Xm[LTT*QQ + idx];
    float vo = Xv[LTT*QQ + idx];
    float s1 = vo + mo*mo;
    float s2 = logf(vo);
    float s3 = 0.f;
    if (idx < LTT*QQ) { float mb = Xm[idx], vb = Xv[idx]; s3 = mb*mb + vb; }
    for (int off = 32; off; off >>= 1) {
        s1 += __shfl_xor(s1, off, 64);
        s2 += __shfl_xor(s2, off, 64);
        s3 += __shfl_xor(s3, off, 64);
    }
    if ((threadIdx.x & 63) == 0) {
        atomicAdd(&sums[0], s1);
        atomicAdd(&sums[1], s2);
        atomicAdd(&sums[2], s3);
    }
}

// ---------------- final assembly ----------------
__global__ __launch_bounds__(256) void final_kernel(
    const float* __restrict__ varp, const float* __restrict__ C1g, const float* __restrict__ C2g,
    const float* __restrict__ Linvg, const float* __restrict__ tmpg,
    const float* __restrict__ Wg, const float* __restrict__ sums, float* __restrict__ out)
{
    __shared__ float r1[256], r2[256], r3[256];
    int tid = threadIdx.x;
    float tr = 0.f, ld = 0.f, c2 = 0.f;
    for (int idx = tid; idx < MM*MM; idx += 256) tr += tmpg[idx]*Linvg[idx];
    if (tid < MM) ld = logf(C2g[tid*MM+tid]) - logf(C1g[tid*MM+tid]);
    for (int idx = tid; idx < MM*QQ; idx += 256) c2 += Wg[idx]*Wg[idx];
    r1[tid] = tr; r2[tid] = ld; r3[tid] = c2;
    __syncthreads();
    for (int s = 128; s; s >>= 1) {
        if (tid < s) { r1[tid] += r1[tid+s]; r2[tid] += r2[tid+s]; r3[tid] += r3[tid+s]; }
        __syncthreads();
    }
    if (tid == 0) {
        float var     = varp[0];
        float trAAT   = (1.0f/SIG2) * r1[0];
        float logdetB = 2.0f * r2[0];
        float sumc2   = (1.0f/(SIG2*SIG2)) * r3[0];
        float psi0    = (float)NN * var;
        const float LOG2PI = 1.837877066409345f;
        float NQf = (float)NQ;
        float bound = -0.5f*NQf*(LOG2PI + logf(SIG2));
        bound += -0.5f/SIG2 * sums[0];
        bound += -0.5f*(float)QQ*(psi0/SIG2 - trAAT);
        bound += -0.5f*(float)QQ*logdetB;
        bound += 0.5f*sumc2;
        bound += 0.5f*sums[1] + 0.5f*NQf*LOG2PI;
        bound += -(float)(LTT*QQ)*LOG2PI - 0.5f*sums[2];
        out[0] = bound;
    }
}

extern "C" void kernel_launch(void* const* d_in, const int* in_sizes, int n_in,
                              void* d_out, int out_size, void* d_ws, size_t ws_size,
                              hipStream_t stream)
{
    (void)in_sizes; (void)n_in; (void)out_size; (void)ws_size;
    const float* Xm   = (const float*)d_in[0];
    const float* Xv   = (const float*)d_in[1];
    const float* Zg   = (const float*)d_in[2];
    const float* ls   = (const float*)d_in[3];
    const float* varp = (const float*)d_in[4];

    float* ws = (float*)d_ws;
    float* a_g    = ws;                 // N*32
    float* axm_g  = a_g    + NN*DD;     // N*32
    float* dinv_g = axm_g  + NN*DD;     // N*32
    float* L1_g   = dinv_g + NN*DD;     // N
    float* base1_g= L1_g   + NN;        // N
    float* t2_g   = base1_g+ NN;        // N*M
    float* t3_g   = t2_g   + NN*MM;     // N*M
    float* psi2   = t3_g   + NN*MM;     // M*M
    float* Kuu    = psi2   + MM*MM;     // M*M
    float* C1     = Kuu    + MM*MM;     // M*M
    float* Linv   = C1     + MM*MM;     // M*M
    float* G      = Linv   + MM*MM;     // M*M
    float* C2     = G      + MM*MM;     // M*M
    float* tmpm   = C2     + MM*MM;     // M*M
    float* Yg     = tmpm   + MM*MM;     // M*Q
    float* Wg     = Yg     + MM*QQ;     // M*Q
    float* sums   = Wg     + MM*QQ;     // 4

    hipMemsetAsync(psi2, 0, MM*MM*sizeof(float), stream);
    hipMemsetAsync(Yg,   0, MM*QQ*sizeof(float), stream);
    hipMemsetAsync(sums, 0, 4*sizeof(float), stream);

    prep_kernel<<<NN/256, 256, 0, stream>>>(Xm, Xv, ls, varp, a_g, axm_g, dinv_g, L1_g, base1_g);
    k1_kernel<<<dim3(NN/256, MM), 256, 0, stream>>>(Xm, Zg, a_g, axm_g, dinv_g, base1_g, t2_g, t3_g, Yg);
    kuu_kernel<<<MM*MM/256, 256, 0, stream>>>(Zg, ls, varp, Kuu);
    chol_kernel<<<1, 256, 0, stream>>>(Kuu, C1);
    triinv_kernel<<<MM, 64, 0, stream>>>(C1, Linv);
    psi2_kernel<<<dim3(4, 128), 256, 0, stream>>>(Zg, ls, a_g, L1_g, t2_g, t3_g, psi2);
    gadd_kernel<<<MM*MM/256, 256, 0, stream>>>(Kuu, psi2, G);
    chol_kernel<<<1, 256, 0, stream>>>(G, C2);
    trisolve_kernel<<<QQ, 64, 0, stream>>>(C2, Yg, Wg);
    tmpmul_kernel<<<MM*MM/256, 256, 0, stream>>>(Linv, psi2, tmpm);
    stats_kernel<<<NQ/256, 256, 0, stream>>>(Xm, Xv, sums);
    final_kernel<<<1, 256, 0, stream>>>(varp, C1, C2, Linv, tmpm, Wg, sums, (float*)d_out);
}

// Round 2
// 654.014 us; speedup vs baseline: 1.3722x; 1.3722x over previous
//
#include <hip/hip_runtime.h>

#define NN   4096
#define NQ   (NN*4)
#define QQ   4
#define LTT  8
#define DD   32
#define MM   128
#define SIG2 0.001f
#define JIT  1e-5f
#define LOG2E 1.4426950408889634f

typedef _Float16 half8 __attribute__((ext_vector_type(8)));
typedef float    f32x4 __attribute__((ext_vector_type(4)));

__device__ __forceinline__ float fexp2(float x) {
#if __has_builtin(__builtin_amdgcn_exp2f)
    return __builtin_amdgcn_exp2f(x);
#else
    return exp2f(x);
#endif
}

// ---------------- per-n precompute + scalar stats ----------------
__global__ __launch_bounds__(256) void prep_kernel(
    const float* __restrict__ Xm, const float* __restrict__ Xv,
    const float* __restrict__ ls, const float* __restrict__ varp,
    float4* __restrict__ pk4, _Float16* __restrict__ bh,
    float* __restrict__ L1p, float* __restrict__ bbp, float* __restrict__ sums)
{
    int n = blockIdx.x * 256 + threadIdx.x;
    float var = varp[0];
    float slog2 = 0.f, slog1 = 0.f, T1 = 0.f, c0 = 0.f;
    #pragma unroll 8
    for (int q = 0; q < DD; ++q) {
        float xm = Xm[n*QQ + q];
        float xv = Xv[n*QQ + q];
        float l  = ls[q];
        float l2 = l*l;
        float a    = 1.0f / (2.0f*xv + l2);
        float dinv = 1.0f / (l2 + xv);
        float4 v;
        v.x = LOG2E * a * xm;          // scaled axm
        v.y = LOG2E * (-0.25f * a);    // scaled -a/4
        v.z = dinv;
        v.w = -2.0f * dinv * xm;
        pk4[n*DD + q] = v;
        bh[n*DD + q] = (_Float16)(0.5f * LOG2E * (1.0f/l2 - a));
        slog2 += log1pf(2.0f*xv/l2);
        slog1 += log1pf(xv/l2);
        T1    += a*xm*xm;
        c0    += dinv*xm*xm;
    }
    L1p[n] = 0.5f * LOG2E * (2.0f*logf(var) - 0.5f*slog2 - T1);
    bbp[n] = logf(var) - 0.5f*slog1 - 0.5f*c0;

    // stats: this thread handles observed row n+LTT, and boundary rows n<LTT
    float s1 = 0.f, s2 = 0.f, s3 = 0.f;
    #pragma unroll
    for (int c = 0; c < QQ; ++c) {
        float mo = Xm[(n+LTT)*QQ + c];
        float vo = Xv[(n+LTT)*QQ + c];
        s1 += vo + mo*mo;
        s2 += logf(vo);
    }
    if (n < LTT) {
        #pragma unroll
        for (int c = 0; c < QQ; ++c) {
            float mb = Xm[n*QQ+c], vb = Xv[n*QQ+c];
            s3 += mb*mb + vb;
        }
    }
    for (int off = 32; off; off >>= 1) {
        s1 += __shfl_xor(s1, off, 64);
        s2 += __shfl_xor(s2, off, 64);
        s3 += __shfl_xor(s3, off, 64);
    }
    if ((threadIdx.x & 63) == 0) {
        atomicAdd(&sums[0], s1);
        atomicAdd(&sums[1], s2);
        atomicAdd(&sums[2], s3);
    }
}

// -------- Z-side statics: Kuu (blocks 0..63), s[m] + Zh f16 (block 64) --------
__global__ __launch_bounds__(256) void static_kernel(
    const float* __restrict__ Zg, const float* __restrict__ ls,
    const float* __restrict__ varp, float* __restrict__ Kuu,
    float* __restrict__ sp, _Float16* __restrict__ Zh)
{
    int b = blockIdx.x, tid = threadIdx.x;
    if (b < 64) {
        int idx = b*256 + tid;
        int i = idx >> 7, j = idx & 127;
        float var = varp[0];
        float s = 0.f;
        for (int q = 0; q < DD; ++q) {
            float l = ls[q];
            float d = (Zg[i*DD+q] - Zg[j*DD+q]) / l;
            s += d*d;
        }
        float v = var * __expf(-0.5f*s);
        if (i == j) v += JIT;
        Kuu[idx] = v;
    } else {
        if (tid < MM) {
            float s = 0.f;
            for (int q = 0; q < DD; ++q) {
                float l = ls[q]; float z = Zg[tid*DD+q];
                s += z*z / (4.0f*l*l);
            }
            sp[tid] = LOG2E * s;
        }
        for (int e = tid; e < MM*DD; e += 256) Zh[e] = (_Float16)Zg[e];
    }
}

// -------- k1: r[n,m] (log2-domain row terms) + Y = psi1^T X_mo --------
__global__ __launch_bounds__(256) void k1_kernel(
    const float* __restrict__ Xm, const float* __restrict__ Zg,
    const float4* __restrict__ pk4, const float* __restrict__ L1p,
    const float* __restrict__ bbp, const float* __restrict__ sp,
    float* __restrict__ r_g, float* __restrict__ Yg)
{
    __shared__ float Zl[MM*33];
    __shared__ float yred[MM*QQ];
    int tid = threadIdx.x;
    for (int e = tid; e < MM*DD; e += 256)
        Zl[(e>>5)*33 + (e&31)] = Zg[e];
    __syncthreads();

    int m  = tid & 127;
    int nh = __builtin_amdgcn_readfirstlane(tid >> 7);
    float zr[DD];
    #pragma unroll
    for (int q = 0; q < DD; ++q) zr[q] = Zl[m*33 + q];
    float sm = sp[m];

    float y0 = 0.f, y1 = 0.f, y2 = 0.f, y3 = 0.f;
    int n0 = blockIdx.x*16 + nh*8;
    for (int i = 0; i < 8; ++i) {
        int n = n0 + i;
        float L1n = L1p[n], bbn = bbp[n];
        const float4* pkn = pk4 + n*DD;
        float racc = 0.f, q1 = 0.f;
        #pragma unroll
        for (int q = 0; q < DD; ++q) {
            float4 v = pkn[q];
            float z = zr[q];
            racc = fmaf(v.x, z, racc);
            racc = fmaf(v.y, z*z, racc);
            float t = fmaf(v.z, z, v.w);
            q1 = fmaf(t, z, q1);
        }
        r_g[n*MM + m] = L1n + racc - sm;
        float p1 = __expf(fmaf(-0.5f, q1, bbn));
        float4 xo = *(const float4*)(Xm + (LTT+n)*QQ);
        y0 = fmaf(p1, xo.x, y0); y1 = fmaf(p1, xo.y, y1);
        y2 = fmaf(p1, xo.z, y2); y3 = fmaf(p1, xo.w, y3);
    }
    if (nh == 0) {
        yred[m*4+0] = y0; yred[m*4+1] = y1; yred[m*4+2] = y2; yred[m*4+3] = y3;
    }
    __syncthreads();
    if (nh == 1) {
        yred[m*4+0] += y0; yred[m*4+1] += y1; yred[m*4+2] += y2; yred[m*4+3] += y3;
    }
    __syncthreads();
    for (int e = tid; e < MM*QQ; e += 256) atomicAdd(&Yg[e], yred[e]);
}

// ---------------- 128x128 Cholesky, single block ----------------
__global__ __launch_bounds__(256) void chol_kernel(const float* __restrict__ Ain,
                                                   float* __restrict__ Lout)
{
    __shared__ float mat[MM*129];
    int tid = threadIdx.x;
    for (int idx = tid; idx < MM*MM; idx += 256) {
        int i = idx >> 7, j = idx & 127;
        mat[i*129+j] = Ain[idx];
    }
    __syncthreads();
    int tx = tid & 15, ty = tid >> 4;
    for (int k = 0; k < MM; ++k) {
        float dk  = sqrtf(mat[k*129+k]);
        float rdk = 1.0f/dk;
        for (int i = k+1+tid; i < MM; i += 256) mat[i*129+k] *= rdk;
        __syncthreads();
        if (tid == 0) mat[k*129+k] = dk;
        for (int i = k+1+ty; i < MM; i += 16) {
            float lik = mat[i*129+k];
            for (int j = k+1+tx; j <= i; j += 16) mat[i*129+j] -= lik*mat[j*129+k];
        }
        __syncthreads();
    }
    for (int idx = tid; idx < MM*MM; idx += 256) {
        int i = idx >> 7, j = idx & 127;
        Lout[idx] = (j <= i) ? mat[i*129+j] : 0.f;
    }
}

// ------- lower-tri inverse, one wave per column -------
__global__ __launch_bounds__(64) void triinv_kernel(const float* __restrict__ Lg,
                                                    float* __restrict__ Xout)
{
    int c = blockIdx.x, lane = threadIdx.x;
    __shared__ float x[MM];
    if (lane == 0) x[c] = 1.0f / Lg[c*MM+c];
    __syncthreads();
    for (int i = c+1; i < MM; ++i) {
        float p = 0.f;
        for (int j = c+lane; j < i; j += 64) p += Lg[i*MM+j]*x[j];
        for (int off = 32; off; off >>= 1) p += __shfl_xor(p, off, 64);
        if (lane == 0) x[i] = -p / Lg[i*MM+i];
        __syncthreads();
    }
    for (int i = lane; i < MM; i += 64) Xout[i*MM+c] = (i < c) ? 0.f : x[i];
}

// ------- triangular solve, 4 RHS -------
__global__ __launch_bounds__(64) void trisolve_kernel(const float* __restrict__ Lg,
                                                      const float* __restrict__ Yg,
                                                      float* __restrict__ Wg)
{
    int c = blockIdx.x, lane = threadIdx.x;
    __shared__ float x[MM];
    for (int i = 0; i < MM; ++i) {
        float p = 0.f;
        for (int j = lane; j < i; j += 64) p += Lg[i*MM+j]*x[j];
        for (int off = 32; off; off >>= 1) p += __shfl_xor(p, off, 64);
        if (lane == 0) x[i] = (Yg[i*QQ+c] - p) / Lg[i*MM+i];
        __syncthreads();
    }
    for (int i = lane; i < MM; i += 64) Wg[i*QQ+c] = x[i];
}

// ---------------- psi2 via f16 MFMA ----------------
__global__ __launch_bounds__(256) void psi2_kernel(
    const _Float16* __restrict__ Zh, const float* __restrict__ r_g,
    const _Float16* __restrict__ bh, float* __restrict__ psi2)
{
    __shared__ float rl[8][MM];
    __shared__ float rt[8][16][12];
    __shared__ _Float16 bl[8][DD];
    int tid = threadIdx.x;
    int w  = tid >> 6;
    int l  = tid & 63;
    int lm = l & 15;
    int lg = l >> 4;
    int rh = blockIdx.x & 1;
    int nc = blockIdx.x >> 1;
    int st = rh*4 + w;               // this wave's m-tile (0..7)

    // B fragments: Z rows for all 8 k-tiles, f16, in registers
    half8 B[8];
    #pragma unroll
    for (int kt = 0; kt < 8; ++kt)
        B[kt] = ((const half8*)Zh)[(kt*16 + lm)*4 + lg];
    // this wave's own strip fragment (avoid runtime-indexing B[])
    half8 Zst = ((const half8*)Zh)[(st*16 + lm)*4 + lg];

    f32x4 z4; z4[0]=0.f; z4[1]=0.f; z4[2]=0.f; z4[3]=0.f;
    f32x4 acc[8];
    #pragma unroll
    for (int kt = 0; kt < 8; ++kt) acc[kt] = z4;

    for (int ch = 0; ch < 2; ++ch) {
        int n0 = nc*16 + ch*8;
        __syncthreads();
        for (int e = tid; e < 8*MM; e += 256) {
            int nn = e >> 7, j = e & 127;
            float v = r_g[(n0+nn)*MM + j];
            rl[nn][j] = v;
            rt[nn][j & 15][j >> 4] = v;
        }
        { int e = tid; bl[e>>5][e&31] = bh[(n0 + (e>>5))*DD + (e&31)]; }
        __syncthreads();

        for (int i = 0; i < 8; ++i) {
            half8 bf = *(const half8*)&bl[i][lg*8];
            half8 A = Zst * bf;                        // v_pk_mul_f16 x4
            f32x4 rm  = *(const f32x4*)&rl[i][st*16 + lg*4];
            f32x4 rka = *(const f32x4*)&rt[i][lm][0];
            f32x4 rkb = *(const f32x4*)&rt[i][lm][4];
            #pragma unroll
            for (int kt = 0; kt < 8; ++kt) {
                f32x4 p = __builtin_amdgcn_mfma_f32_16x16x32_f16(A, B[kt], z4, 0, 0, 0);
                float rk = (kt < 4) ? rka[kt] : rkb[kt-4];
                #pragma unroll
                for (int j = 0; j < 4; ++j)
                    acc[kt][j] += fexp2(p[j] + rm[j] + rk);
            }
        }
    }
    #pragma unroll
    for (int kt = 0; kt < 8; ++kt)
        #pragma unroll
        for (int j = 0; j < 4; ++j)
            atomicAdd(&psi2[(st*16 + lg*4 + j)*MM + kt*16 + lm], acc[kt][j]);
}

// ---------------- G = Kuu + psi2/sigma2 ----------------
__global__ __launch_bounds__(256) void gadd_kernel(const float* __restrict__ Kuu,
                                                   const float* __restrict__ psi2,
                                                   float* __restrict__ G)
{
    int idx = blockIdx.x*256 + threadIdx.x;
    G[idx] = Kuu[idx] + (1.0f/SIG2)*psi2[idx];
}

// ---------------- tmp = Linv @ psi2 ----------------
__global__ __launch_bounds__(256) void tmpmul_kernel(const float* __restrict__ Linvg,
                                                     const float* __restrict__ psi2,
                                                     float* __restrict__ tmpg)
{
    int idx = blockIdx.x*256 + threadIdx.x;
    int i = idx >> 7, p = idx & 127;
    float s = 0.f;
    for (int j = 0; j < MM; ++j) s += Linvg[i*MM+j]*psi2[j*MM+p];
    tmpg[idx] = s;
}

// ---------------- final assembly ----------------
__global__ __launch_bounds__(256) void final_kernel(
    const float* __restrict__ varp, const float* __restrict__ C1g, const float* __restrict__ C2g,
    const float* __restrict__ Linvg, const float* __restrict__ tmpg,
    const float* __restrict__ Wg, const float* __restrict__ sums, float* __restrict__ out)
{
    __shared__ float r1[256], r2[256], r3[256];
    int tid = threadIdx.x;
    float tr = 0.f, ld = 0.f, c2 = 0.f;
    for (int idx = tid; idx < MM*MM; idx += 256) tr += tmpg[idx]*Linvg[idx];
    if (tid < MM) ld = logf(C2g[tid*MM+tid]) - logf(C1g[tid*MM+tid]);
    for (int idx = tid; idx < MM*QQ; idx += 256) c2 += Wg[idx]*Wg[idx];
    r1[tid] = tr; r2[tid] = ld; r3[tid] = c2;
    __syncthreads();
    for (int s = 128; s; s >>= 1) {
        if (tid < s) { r1[tid] += r1[tid+s]; r2[tid] += r2[tid+s]; r3[tid] += r3[tid+s]; }
        __syncthreads();
    }
    if (tid == 0) {
        float var     = varp[0];
        float trAAT   = (1.0f/SIG2) * r1[0];
        float logdetB = 2.0f * r2[0];
        float sumc2   = (1.0f/(SIG2*SIG2)) * r3[0];
        float psi0    = (float)NN * var;
        const float LOG2PI = 1.837877066409345f;
        float NQf = (float)NQ;
        float bound = -0.5f*NQf*(LOG2PI + logf(SIG2));
        bound += -0.5f/SIG2 * sums[0];
        bound += -0.5f*(float)QQ*(psi0/SIG2 - trAAT);
        bound += -0.5f*(float)QQ*logdetB;
        bound += 0.5f*sumc2;
        bound += 0.5f*sums[1] + 0.5f*NQf*LOG2PI;
        bound += -(float)(LTT*QQ)*LOG2PI - 0.5f*sums[2];
        out[0] = bound;
    }
}

extern "C" void kernel_launch(void* const* d_in, const int* in_sizes, int n_in,
                              void* d_out, int out_size, void* d_ws, size_t ws_size,
                              hipStream_t stream)
{
    (void)in_sizes; (void)n_in; (void)out_size; (void)ws_size;
    const float* Xm   = (const float*)d_in[0];
    const float* Xv   = (const float*)d_in[1];
    const float* Zg   = (const float*)d_in[2];
    const float* ls   = (const float*)d_in[3];
    const float* varp = (const float*)d_in[4];

    float* ws = (float*)d_ws;
    float4*    pk4 = (float4*)ws;                       // N*32 float4 = N*128 f
    float*     p   = ws + NN*MM;
    _Float16*  bhp = (_Float16*)p;  p += NN*DD/2;       // N*32 halves
    _Float16*  Zh  = (_Float16*)p;  p += (MM*DD)/2;     // 4096 halves
    float*     L1p = p;  p += NN;
    float*     bbp = p;  p += NN;
    float*     sp  = p;  p += MM;
    float*     r_g = p;  p += NN*MM;                    // 2 MB
    float*     psi2= p;  p += MM*MM;
    float*     Kuu = p;  p += MM*MM;
    float*     C1  = p;  p += MM*MM;
    float*     Linv= p;  p += MM*MM;
    float*     G   = p;  p += MM*MM;
    float*     C2  = p;  p += MM*MM;
    float*     tmpm= p;  p += MM*MM;
    float*     Yg  = p;  p += MM*QQ;
    float*     Wg  = p;  p += MM*QQ;
    float*     sums= p;  p += 4;

    hipMemsetAsync(psi2, 0, MM*MM*sizeof(float), stream);
    hipMemsetAsync(Yg,   0, MM*QQ*sizeof(float), stream);
    hipMemsetAsync(sums, 0, 4*sizeof(float), stream);

    prep_kernel<<<NN/256, 256, 0, stream>>>(Xm, Xv, ls, varp, pk4, bhp, L1p, bbp, sums);
    static_kernel<<<65, 256, 0, stream>>>(Zg, ls, varp, Kuu, sp, Zh);
    k1_kernel<<<NN/16, 256, 0, stream>>>(Xm, Zg, pk4, L1p, bbp, sp, r_g, Yg);
    chol_kernel<<<1, 256, 0, stream>>>(Kuu, C1);
    triinv_kernel<<<MM, 64, 0, stream>>>(C1, Linv);
    psi2_kernel<<<512, 256, 0, stream>>>(Zh, r_g, bhp, psi2);
    gadd_kernel<<<MM*MM/256, 256, 0, stream>>>(Kuu, psi2, G);
    chol_kernel<<<1, 256, 0, stream>>>(G, C2);
    trisolve_kernel<<<QQ, 64, 0, stream>>>(C2, Yg, Wg);
    tmpmul_kernel<<<MM*MM/256, 256, 0, stream>>>(Linv, psi2, tmpm);
    stats_is_in_prep:;
    final_kernel<<<1, 256, 0, stream>>>(varp, C1, C2, Linv, tmpm, Wg, sums, (float*)d_out);
}

// Round 3
// 309.475 us; speedup vs baseline: 2.8999x; 2.1133x over previous
//
#include <hip/hip_runtime.h>

#define NN   4096
#define NQ   (NN*4)
#define QQ   4
#define LTT  8
#define DD   32
#define MM   128
#define SIG2 0.001f
#define JIT  1e-5f
#define LOG2E 1.4426950408889634f

typedef _Float16 half8 __attribute__((ext_vector_type(8)));
typedef float    f32x4 __attribute__((ext_vector_type(4)));

__device__ __forceinline__ float fexp2(float x) {
#if __has_builtin(__builtin_amdgcn_exp2f)
    return __builtin_amdgcn_exp2f(x);
#else
    return exp2f(x);
#endif
}

// ============ prep (blocks 0-15) + Kuu (16-79) + sp/Zh (80) ============
__global__ __launch_bounds__(256) void prepstatic_kernel(
    const float* __restrict__ Xm, const float* __restrict__ Xv,
    const float* __restrict__ Zg, const float* __restrict__ ls,
    const float* __restrict__ varp,
    float4* __restrict__ pk4, _Float16* __restrict__ bh,
    float* __restrict__ L1p, float* __restrict__ bbp, float* __restrict__ sumsP,
    float* __restrict__ Kuu, float* __restrict__ sp, _Float16* __restrict__ Zh)
{
    int b = blockIdx.x, tid = threadIdx.x;
    if (b < 16) {
        __shared__ float ra[256], rb[256], rc[256];
        int n = b*256 + tid;
        float var = varp[0];
        float slog2 = 0.f, slog1 = 0.f, T1 = 0.f, c0 = 0.f;
        #pragma unroll 8
        for (int q = 0; q < DD; ++q) {
            float xm = Xm[n*QQ + q];
            float xv = Xv[n*QQ + q];
            float l  = ls[q];
            float l2 = l*l;
            float a    = 1.0f / (2.0f*xv + l2);
            float dinv = 1.0f / (l2 + xv);
            float4 v;
            v.x = LOG2E * a * xm;
            v.y = LOG2E * (-0.25f * a);
            v.z = dinv;
            v.w = -2.0f * dinv * xm;
            pk4[n*DD + q] = v;
            bh[n*DD + q] = (_Float16)(0.5f * LOG2E * (1.0f/l2 - a));
            slog2 += log1pf(2.0f*xv/l2);
            slog1 += log1pf(xv/l2);
            T1    += a*xm*xm;
            c0    += dinv*xm*xm;
        }
        L1p[n] = 0.5f * LOG2E * (2.0f*logf(var) - 0.5f*slog2 - T1);
        bbp[n] = logf(var) - 0.5f*slog1 - 0.5f*c0;
        float s1 = 0.f, s2 = 0.f, s3 = 0.f;
        #pragma unroll
        for (int c = 0; c < QQ; ++c) {
            float mo = Xm[(n+LTT)*QQ + c];
            float vo = Xv[(n+LTT)*QQ + c];
            s1 += vo + mo*mo;
            s2 += logf(vo);
        }
        if (n < LTT) {
            #pragma unroll
            for (int c = 0; c < QQ; ++c) {
                float mb = Xm[n*QQ+c], vb = Xv[n*QQ+c];
                s3 += mb*mb + vb;
            }
        }
        ra[tid]=s1; rb[tid]=s2; rc[tid]=s3;
        __syncthreads();
        for (int s = 128; s; s >>= 1) {
            if (tid < s) { ra[tid]+=ra[tid+s]; rb[tid]+=rb[tid+s]; rc[tid]+=rc[tid+s]; }
            __syncthreads();
        }
        if (tid == 0) { sumsP[b*3+0]=ra[0]; sumsP[b*3+1]=rb[0]; sumsP[b*3+2]=rc[0]; }
    } else if (b < 80) {
        int idx = (b-16)*256 + tid;
        int i = idx >> 7, j = idx & 127;
        float var = varp[0];
        float s = 0.f;
        for (int q = 0; q < DD; ++q) {
            float l = ls[q];
            float d = (Zg[i*DD+q] - Zg[j*DD+q]) / l;
            s += d*d;
        }
        float v = var * __expf(-0.5f*s);
        if (i == j) v += JIT;
        Kuu[idx] = v;
    } else {
        if (tid < MM) {
            float s = 0.f;
            for (int q = 0; q < DD; ++q) {
                float l = ls[q]; float z = Zg[tid*DD+q];
                s += z*z / (4.0f*l*l);
            }
            sp[tid] = LOG2E * s;
        }
        for (int e = tid; e < MM*DD; e += 256) Zh[e] = (_Float16)Zg[e];
    }
}

// ============ k1: r[n,m] + per-block Y partials ============
__global__ __launch_bounds__(256) void k1_kernel(
    const float* __restrict__ Xm, const float* __restrict__ Zg,
    const float4* __restrict__ pk4, const float* __restrict__ L1p,
    const float* __restrict__ bbp, const float* __restrict__ sp,
    float* __restrict__ r_g, float* __restrict__ Yp)
{
    __shared__ float Zl[MM*33];
    __shared__ float yredl[MM*QQ];
    int tid = threadIdx.x;
    for (int e = tid; e < MM*DD; e += 256)
        Zl[(e>>5)*33 + (e&31)] = Zg[e];
    __syncthreads();
    int m = tid & 127, half = tid >> 7;
    float zr[DD];
    #pragma unroll
    for (int q = 0; q < DD; ++q) zr[q] = Zl[m*33 + q];
    float sm = sp[m];
    float y0=0.f, y1=0.f, y2=0.f, y3=0.f;
    int n0 = blockIdx.x*32 + half*16;
    for (int i = 0; i < 16; ++i) {
        int n = n0 + i;
        float L1n = L1p[n], bbn = bbp[n];
        const float4* pkn = pk4 + n*DD;
        float racc = 0.f, q1 = 0.f;
        #pragma unroll
        for (int q = 0; q < DD; ++q) {
            float4 v = pkn[q];
            float z = zr[q];
            racc = fmaf(v.x, z, racc);
            racc = fmaf(v.y, z*z, racc);
            float t = fmaf(v.z, z, v.w);
            q1 = fmaf(t, z, q1);
        }
        r_g[n*MM + m] = L1n + racc - sm;
        float p1 = __expf(fmaf(-0.5f, q1, bbn));
        float4 xo = *(const float4*)(Xm + (LTT+n)*QQ);
        y0 = fmaf(p1, xo.x, y0); y1 = fmaf(p1, xo.y, y1);
        y2 = fmaf(p1, xo.z, y2); y3 = fmaf(p1, xo.w, y3);
    }
    if (half == 0) {
        yredl[m*4+0]=y0; yredl[m*4+1]=y1; yredl[m*4+2]=y2; yredl[m*4+3]=y3;
    }
    __syncthreads();
    if (half == 1) {
        yredl[m*4+0]+=y0; yredl[m*4+1]+=y1; yredl[m*4+2]+=y2; yredl[m*4+3]+=y3;
    }
    __syncthreads();
    for (int e = tid; e < 512; e += 256) Yp[blockIdx.x*512 + e] = yredl[e];
}

// ============ psi2: MFMA, partial slabs, no atomics ============
__global__ __launch_bounds__(256) void psi2_kernel(
    const _Float16* __restrict__ Zh, const float* __restrict__ r_g,
    const _Float16* __restrict__ bh, float* __restrict__ psi2p)
{
    int tid = threadIdx.x;
    int w = tid >> 6, l = tid & 63, lm = l & 15, lg = l >> 4;
    int t = blockIdx.x, mt = t >> 3, kt = t & 7;
    int nq = blockIdx.y;
    half8 Bf = ((const half8*)Zh)[(kt*16 + lm)*4 + lg];
    half8 Zm = ((const half8*)Zh)[(mt*16 + lm)*4 + lg];
    f32x4 z4; z4[0]=0.f; z4[1]=0.f; z4[2]=0.f; z4[3]=0.f;
    f32x4 acc = z4;
    int n0 = nq*1024 + w*256;
    for (int n = n0; n < n0+256; ++n) {
        half8 bf = ((const half8*)bh)[n*4 + lg];
        half8 A = Zm * bf;
        f32x4 rm = *(const f32x4*)(r_g + n*MM + mt*16 + lg*4);
        float rk = r_g[n*MM + kt*16 + lm];
        f32x4 p = __builtin_amdgcn_mfma_f32_16x16x32_f16(A, Bf, z4, 0, 0, 0);
        acc[0] += fexp2(p[0] + rm[0] + rk);
        acc[1] += fexp2(p[1] + rm[1] + rk);
        acc[2] += fexp2(p[2] + rm[2] + rk);
        acc[3] += fexp2(p[3] + rm[3] + rk);
    }
    float* dst = psi2p + (nq*4 + w)*16384;
    #pragma unroll
    for (int j = 0; j < 4; ++j)
        dst[(mt*16 + lg*4 + j)*MM + kt*16 + lm] = acc[j];
}

// ============ shared linalg device functions (LDS stride 132) ============
__device__ __forceinline__ void dev_chol(float* mat, int tid)
{
    int wv = tid >> 6, ln = tid & 63;
    for (int p = 0; p < 8; ++p) {
        int base = p*16;
        if (wv == 0) {
            int r0 = base + ln, r1 = r0 + 64;
            bool h0 = r0 < 128, h1 = r1 < 128;
            float a0[16], a1[16];
            #pragma unroll
            for (int c = 0; c < 16; ++c) {
                a0[c] = h0 ? mat[r0*132 + base + c] : 0.f;
                a1[c] = h1 ? mat[r1*132 + base + c] : 0.f;
            }
            #pragma unroll
            for (int kk = 0; kk < 16; ++kk) {
                float d = __shfl(a0[kk], kk, 64);
                float sq = sqrtf(d);
                float rdk = 1.0f / sq;
                if (ln > kk) a0[kk] *= rdk;
                if (ln == kk) a0[kk] = sq;
                a1[kk] *= rdk;
                float lj[16];
                #pragma unroll
                for (int j = kk+1; j < 16; ++j) lj[j] = __shfl(a0[kk], j, 64);
                #pragma unroll
                for (int j = kk+1; j < 16; ++j) {
                    a0[j] -= a0[kk] * lj[j];
                    a1[j] -= a1[kk] * lj[j];
                }
            }
            #pragma unroll
            for (int c = 0; c < 16; ++c) {
                if (h0) mat[r0*132 + base + c] = a0[c];
                if (h1) mat[r1*132 + base + c] = a1[c];
            }
        }
        __syncthreads();
        int S = 112 - base;
        if (S > 0) {
            int T = S >> 2, nb = base + 16;
            for (int t = tid; t < T*T; t += 256) {
                int ti = t / T, tj = t - ti*T;
                if (tj <= ti) {
                    int i0 = nb + ti*4, j0 = nb + tj*4;
                    float ac[4][4];
                    #pragma unroll
                    for (int r = 0; r < 4; ++r)
                        #pragma unroll
                        for (int s = 0; s < 4; ++s) ac[r][s] = mat[(i0+r)*132 + j0 + s];
                    #pragma unroll
                    for (int c4 = 0; c4 < 4; ++c4) {
                        float4 av[4], bv[4];
                        #pragma unroll
                        for (int r = 0; r < 4; ++r) {
                            av[r] = *(const float4*)&mat[(i0+r)*132 + base + c4*4];
                            bv[r] = *(const float4*)&mat[(j0+r)*132 + base + c4*4];
                        }
                        #pragma unroll
                        for (int r = 0; r < 4; ++r)
                            #pragma unroll
                            for (int s = 0; s < 4; ++s)
                                ac[r][s] -= av[r].x*bv[s].x + av[r].y*bv[s].y
                                          + av[r].z*bv[s].z + av[r].w*bv[s].w;
                    }
                    #pragma unroll
                    for (int r = 0; r < 4; ++r)
                        #pragma unroll
                        for (int s = 0; s < 4; ++s) mat[(i0+r)*132 + j0 + s] = ac[r][s];
                }
            }
        }
        __syncthreads();
    }
}

// invert the 8 diagonal 16x16 lower-tri blocks; dinvb[bd*256 + i*16 + c] (upper = 0)
__device__ __forceinline__ void dev_dinv(const float* mat, float* dinvb, int tid)
{
    int wv = tid >> 6, ln = tid & 63;
    if (ln < 16) {
        int c = ln;
        for (int half = 0; half < 2; ++half) {
            int bd = wv + half*4, base = bd*16;
            float x[16];
            #pragma unroll
            for (int i = 0; i < 16; ++i) {
                float dii = mat[(base+i)*132 + base + i];
                float s = 0.f;
                #pragma unroll
                for (int j = 0; j < i; ++j) s += mat[(base+i)*132 + base + j] * x[j];
                float v;
                if (i < c) v = 0.f;
                else if (i == c) v = 1.0f / dii;
                else v = -s / dii;
                x[i] = v;
            }
            #pragma unroll
            for (int i = 0; i < 16; ++i) dinvb[bd*256 + i*16 + c] = x[i];
        }
    }
    __syncthreads();
}

// in-place blocked forward solve: rhs (128 x C) := L^{-1} rhs
template<int C>
__device__ __forceinline__ void dev_solve(const float* mat, const float* dinvb,
                                          float* tmp, float* rhs, int tid)
{
    const int AT = 16*C;
    int r = tid / C, cc = tid % C;
    for (int bi = 0; bi < 8; ++bi) {
        float acc = 0.f;
        if (tid < AT) {
            acc = rhs[(bi*16+r)*C + cc];
            for (int bk = 0; bk < bi; ++bk) {
                #pragma unroll
                for (int kk = 0; kk < 16; ++kk)
                    acc -= mat[(bi*16+r)*132 + bk*16+kk] * rhs[(bk*16+kk)*C + cc];
            }
        }
        __syncthreads();
        if (tid < AT) tmp[r*C + cc] = acc;
        __syncthreads();
        if (tid < AT) {
            float w = 0.f;
            #pragma unroll
            for (int kk = 0; kk < 16; ++kk)
                w += dinvb[bi*256 + r*16 + kk] * tmp[kk*C + cc];
            rhs[(bi*16+r)*C + cc] = w;
        }
        __syncthreads();
    }
}

// ============ linalg: block0 = chol(Kuu)+Dinv+store; block1 = chol(G)+u-solve ============
__global__ __launch_bounds__(256) void linalg_kernel(
    const float* __restrict__ Kuu, const float* __restrict__ psi2p,
    const float* __restrict__ Yp,
    float* __restrict__ Lg, float* __restrict__ Dinvg, float* __restrict__ scalars)
{
    __shared__ float mat[128*132];
    __shared__ float dinvb[8*256];
    __shared__ float tmp[16*8];
    __shared__ float rhs[128*4];
    __shared__ float red[256];
    int tid = threadIdx.x;
    if (blockIdx.x == 0) {
        for (int e = tid; e < 16384; e += 256) mat[(e>>7)*132 + (e&127)] = Kuu[e];
        __syncthreads();
        dev_chol(mat, tid);
        float ld = 0.f;
        if (tid < 128) ld = logf(mat[tid*132 + tid]);
        red[tid] = ld; __syncthreads();
        for (int s = 128; s; s >>= 1) { if (tid < s) red[tid] += red[tid+s]; __syncthreads(); }
        if (tid == 0) scalars[0] = red[0];
        dev_dinv(mat, dinvb, tid);
        for (int e = tid; e < 16384; e += 256) Lg[e] = mat[(e>>7)*132 + (e&127)];
        for (int e = tid; e < 2048; e += 256) Dinvg[e] = dinvb[e];
    } else {
        for (int e = tid; e < 16384; e += 256) {
            float s = 0.f;
            #pragma unroll
            for (int sl = 0; sl < 16; ++sl) s += psi2p[sl*16384 + e];
            mat[(e>>7)*132 + (e&127)] = Kuu[e] + (1.0f/SIG2)*s;
        }
        __syncthreads();
        dev_chol(mat, tid);
        float ld = 0.f;
        if (tid < 128) ld = logf(mat[tid*132 + tid]);
        red[tid] = ld; __syncthreads();
        for (int s = 128; s; s >>= 1) { if (tid < s) red[tid] += red[tid+s]; __syncthreads(); }
        if (tid == 0) scalars[1] = red[0];
        dev_dinv(mat, dinvb, tid);
        for (int e = tid; e < 512; e += 256) {
            float s = 0.f;
            for (int b = 0; b < 128; ++b) s += Yp[b*512 + e];
            rhs[e] = s;
        }
        __syncthreads();
        dev_solve<4>(mat, dinvb, tmp, rhs, tid);
        float c2 = 0.f;
        for (int e = tid; e < 512; e += 256) { float v = rhs[e]; c2 += v*v; }
        red[tid] = c2; __syncthreads();
        for (int s = 128; s; s >>= 1) { if (tid < s) red[tid] += red[tid+s]; __syncthreads(); }
        if (tid == 0) scalars[2] = red[0];
    }
}

// ============ 16-block triangular solves; MODE0: W = L^-1 psi2; MODE1: diag trace ============
template<int MODE>
__global__ __launch_bounds__(256) void solve_kernel(
    const float* __restrict__ Lg, const float* __restrict__ Dinvg,
    const float* __restrict__ psi2p, const float* __restrict__ Win,
    float* __restrict__ Wout, float* __restrict__ scalars)
{
    __shared__ float mat[128*132];
    __shared__ float dinvb[2048];
    __shared__ float rhs[128*8];
    __shared__ float tmp[16*8];
    int tid = threadIdx.x;
    int c0 = blockIdx.x * 8;
    for (int e = tid; e < 16384; e += 256) mat[(e>>7)*132 + (e&127)] = Lg[e];
    for (int e = tid; e < 2048; e += 256) dinvb[e] = Dinvg[e];
    for (int e = tid; e < 1024; e += 256) {
        int i = e >> 3, cc = e & 7;
        float v;
        if (MODE == 0) {
            v = 0.f;
            #pragma unroll
            for (int sl = 0; sl < 16; ++sl) v += psi2p[sl*16384 + i*MM + c0 + cc];
        } else {
            v = Win[(c0+cc)*MM + i];
        }
        rhs[e] = v;
    }
    __syncthreads();
    dev_solve<8>(mat, dinvb, tmp, rhs, tid);
    if (MODE == 0) {
        for (int e = tid; e < 1024; e += 256) Wout[(e>>3)*MM + c0 + (e&7)] = rhs[e];
    } else {
        if (tid == 0) {
            float s = 0.f;
            #pragma unroll
            for (int cc = 0; cc < 8; ++cc) s += rhs[(c0+cc)*8 + cc];
            scalars[3 + blockIdx.x] = s;
        }
    }
}

// ============ final assembly ============
__global__ __launch_bounds__(64) void final_kernel(
    const float* __restrict__ varp, const float* __restrict__ scalars,
    const float* __restrict__ sumsP, float* __restrict__ out)
{
    if (threadIdx.x == 0) {
        float s1=0.f, s2=0.f, s3=0.f;
        for (int b = 0; b < 16; ++b) {
            s1 += sumsP[b*3+0]; s2 += sumsP[b*3+1]; s3 += sumsP[b*3+2];
        }
        float tr_raw = 0.f;
        for (int b = 0; b < 16; ++b) tr_raw += scalars[3+b];
        float var = varp[0];
        float trAAT   = tr_raw / SIG2;
        float logdetB = 2.0f * (scalars[1] - scalars[0]);
        float sumc2   = scalars[2] / (SIG2*SIG2);
        float psi0    = (float)NN * var;
        const float LOG2PI = 1.837877066409345f;
        float NQf = (float)NQ;
        float bound = -0.5f*NQf*(LOG2PI + logf(SIG2));
        bound += -0.5f/SIG2 * s1;
        bound += -0.5f*(float)QQ*(psi0/SIG2 - trAAT);
        bound += -0.5f*(float)QQ*logdetB;
        bound += 0.5f*sumc2;
        bound += 0.5f*s2 + 0.5f*NQf*LOG2PI;
        bound += -(float)(LTT*QQ)*LOG2PI - 0.5f*s3;
        out[0] = bound;
    }
}

extern "C" void kernel_launch(void* const* d_in, const int* in_sizes, int n_in,
                              void* d_out, int out_size, void* d_ws, size_t ws_size,
                              hipStream_t stream)
{
    (void)in_sizes; (void)n_in; (void)out_size; (void)ws_size;
    const float* Xm   = (const float*)d_in[0];
    const float* Xv   = (const float*)d_in[1];
    const float* Zg   = (const float*)d_in[2];
    const float* ls   = (const float*)d_in[3];
    const float* varp = (const float*)d_in[4];

    float* p = (float*)d_ws;
    float4*   pk4   = (float4*)p;       p += NN*DD*4;      // 524288
    float*    r_g   = p;                p += NN*MM;        // 524288
    float*    psi2p = p;                p += 16*MM*MM;     // 262144
    float*    Yp    = p;                p += 128*512;      // 65536
    _Float16* bh    = (_Float16*)p;     p += NN*DD/2;      // 65536 floats
    _Float16* Zh    = (_Float16*)p;     p += MM*DD/2;      // 2048 floats
    float*    L1p   = p;                p += NN;
    float*    bbp   = p;                p += NN;
    float*    sp    = p;                p += MM;
    float*    Kuu   = p;                p += MM*MM;
    float*    Lg    = p;                p += MM*MM;
    float*    Dinvg = p;                p += 2048;
    float*    Wg    = p;                p += MM*MM;
    float*    sumsP = p;                p += 64;
    float*    scalars = p;              p += 32;

    prepstatic_kernel<<<81, 256, 0, stream>>>(Xm, Xv, Zg, ls, varp,
                                              pk4, bh, L1p, bbp, sumsP, Kuu, sp, Zh);
    k1_kernel<<<128, 256, 0, stream>>>(Xm, Zg, pk4, L1p, bbp, sp, r_g, Yp);
    psi2_kernel<<<dim3(64, 4), 256, 0, stream>>>(Zh, r_g, bh, psi2p);
    linalg_kernel<<<2, 256, 0, stream>>>(Kuu, psi2p, Yp, Lg, Dinvg, scalars);
    solve_kernel<0><<<16, 256, 0, stream>>>(Lg, Dinvg, psi2p, (const float*)nullptr, Wg, scalars);
    solve_kernel<1><<<16, 256, 0, stream>>>(Lg, Dinvg, psi2p, Wg, (float*)nullptr, scalars);
    final_kernel<<<1, 64, 0, stream>>>(varp, scalars, sumsP, (float*)d_out);
}

// Round 4
// 285.470 us; speedup vs baseline: 3.1437x; 1.0841x over previous
//
#include <hip/hip_runtime.h>

#define NN   4096
#define NQ   (NN*4)
#define QQ   4
#define LTT  8
#define DD   32
#define MM   128
#define SIG2 0.001f
#define JIT  1e-5f
#define LOG2E 1.4426950408889634f

typedef _Float16 half8 __attribute__((ext_vector_type(8)));
typedef float    f32x4 __attribute__((ext_vector_type(4)));

__device__ __forceinline__ float fexp2(float x) { return exp2f(x); }

__device__ __forceinline__ float rlane(float v, int l) {
    return __uint_as_float(__builtin_amdgcn_readlane(__float_as_uint(v), l));
}

// ============ prep (blocks 0-15) + Kuu (16-79) + sp/Zh (80) ============
__global__ __launch_bounds__(256) void prepstatic_kernel(
    const float* __restrict__ Xm, const float* __restrict__ Xv,
    const float* __restrict__ Zg, const float* __restrict__ ls,
    const float* __restrict__ varp,
    float4* __restrict__ pk4, _Float16* __restrict__ bh,
    float* __restrict__ L1p, float* __restrict__ bbp, float* __restrict__ sumsP,
    float* __restrict__ Kuu, float* __restrict__ sp, _Float16* __restrict__ Zh)
{
    int b = blockIdx.x, tid = threadIdx.x;
    if (b < 16) {
        __shared__ float ra[256], rb[256], rc[256];
        int n = b*256 + tid;
        float var = varp[0];
        float slog2 = 0.f, slog1 = 0.f, T1 = 0.f, c0 = 0.f;
        #pragma unroll 8
        for (int q = 0; q < DD; ++q) {
            float xm = Xm[n*QQ + q];
            float xv = Xv[n*QQ + q];
            float l  = ls[q];
            float l2 = l*l;
            float a    = 1.0f / (2.0f*xv + l2);
            float dinv = 1.0f / (l2 + xv);
            float4 v;
            v.x = LOG2E * a * xm;
            v.y = LOG2E * (-0.25f * a);
            v.z = dinv;
            v.w = -2.0f * dinv * xm;
            pk4[n*DD + q] = v;
            bh[n*DD + q] = (_Float16)(0.5f * LOG2E * (1.0f/l2 - a));
            slog2 += log1pf(2.0f*xv/l2);
            slog1 += log1pf(xv/l2);
            T1    += a*xm*xm;
            c0    += dinv*xm*xm;
        }
        L1p[n] = 0.5f * LOG2E * (2.0f*logf(var) - 0.5f*slog2 - T1);
        bbp[n] = logf(var) - 0.5f*slog1 - 0.5f*c0;
        float s1 = 0.f, s2 = 0.f, s3 = 0.f;
        #pragma unroll
        for (int c = 0; c < QQ; ++c) {
            float mo = Xm[(n+LTT)*QQ + c];
            float vo = Xv[(n+LTT)*QQ + c];
            s1 += vo + mo*mo;
            s2 += logf(vo);
        }
        if (n < LTT) {
            #pragma unroll
            for (int c = 0; c < QQ; ++c) {
                float mb = Xm[n*QQ+c], vb = Xv[n*QQ+c];
                s3 += mb*mb + vb;
            }
        }
        ra[tid]=s1; rb[tid]=s2; rc[tid]=s3;
        __syncthreads();
        for (int s = 128; s; s >>= 1) {
            if (tid < s) { ra[tid]+=ra[tid+s]; rb[tid]+=rb[tid+s]; rc[tid]+=rc[tid+s]; }
            __syncthreads();
        }
        if (tid == 0) { sumsP[b*3+0]=ra[0]; sumsP[b*3+1]=rb[0]; sumsP[b*3+2]=rc[0]; }
    } else if (b < 80) {
        int idx = (b-16)*256 + tid;
        int i = idx >> 7, j = idx & 127;
        float var = varp[0];
        float s = 0.f;
        for (int q = 0; q < DD; ++q) {
            float l = ls[q];
            float d = (Zg[i*DD+q] - Zg[j*DD+q]) / l;
            s += d*d;
        }
        float v = var * __expf(-0.5f*s);
        if (i == j) v += JIT;
        Kuu[idx] = v;
    } else {
        if (tid < MM) {
            float s = 0.f;
            for (int q = 0; q < DD; ++q) {
                float l = ls[q]; float z = Zg[tid*DD+q];
                s += z*z / (4.0f*l*l);
            }
            sp[tid] = LOG2E * s;
        }
        for (int e = tid; e < MM*DD; e += 256) Zh[e] = (_Float16)Zg[e];
    }
}

// ============ k1: r[n,m] + per-block Y partials ============
__global__ __launch_bounds__(256) void k1_kernel(
    const float* __restrict__ Xm, const float* __restrict__ Zg,
    const float4* __restrict__ pk4, const float* __restrict__ L1p,
    const float* __restrict__ bbp, const float* __restrict__ sp,
    float* __restrict__ r_g, float* __restrict__ Yp)
{
    __shared__ float Zl[MM*33];
    __shared__ float yredl[MM*QQ];
    int tid = threadIdx.x;
    for (int e = tid; e < MM*DD; e += 256)
        Zl[(e>>5)*33 + (e&31)] = Zg[e];
    __syncthreads();
    int m = tid & 127, half = tid >> 7;
    float zr[DD];
    #pragma unroll
    for (int q = 0; q < DD; ++q) zr[q] = Zl[m*33 + q];
    float sm = sp[m];
    float y0=0.f, y1=0.f, y2=0.f, y3=0.f;
    int n0 = blockIdx.x*32 + half*16;
    for (int i = 0; i < 16; ++i) {
        int n = n0 + i;
        float L1n = L1p[n], bbn = bbp[n];
        const float4* pkn = pk4 + n*DD;
        float racc = 0.f, q1 = 0.f;
        #pragma unroll
        for (int q = 0; q < DD; ++q) {
            float4 v = pkn[q];
            float z = zr[q];
            racc = fmaf(v.x, z, racc);
            racc = fmaf(v.y, z*z, racc);
            float t = fmaf(v.z, z, v.w);
            q1 = fmaf(t, z, q1);
        }
        r_g[n*MM + m] = L1n + racc - sm;
        float p1 = __expf(fmaf(-0.5f, q1, bbn));
        float4 xo = *(const float4*)(Xm + (LTT+n)*QQ);
        y0 = fmaf(p1, xo.x, y0); y1 = fmaf(p1, xo.y, y1);
        y2 = fmaf(p1, xo.z, y2); y3 = fmaf(p1, xo.w, y3);
    }
    if (half == 0) {
        yredl[m*4+0]=y0; yredl[m*4+1]=y1; yredl[m*4+2]=y2; yredl[m*4+3]=y3;
    }
    __syncthreads();
    if (half == 1) {
        yredl[m*4+0]+=y0; yredl[m*4+1]+=y1; yredl[m*4+2]+=y2; yredl[m*4+3]+=y3;
    }
    __syncthreads();
    for (int e = tid; e < 512; e += 256) Yp[blockIdx.x*512 + e] = yredl[e];
}

// ============ shared linalg device functions (LDS stride 132) ============
__device__ __forceinline__ void dev_chol(float* mat, int tid)
{
    int wv = tid >> 6, ln = tid & 63;
    for (int p = 0; p < 8; ++p) {
        int base = p*16;
        if (wv == 0) {
            int r0 = base + ln, r1 = r0 + 64;
            bool h0 = r0 < 128, h1 = r1 < 128;
            float a0[16], a1[16];
            #pragma unroll
            for (int c = 0; c < 16; ++c) {
                a0[c] = h0 ? mat[r0*132 + base + c] : 0.f;
                a1[c] = h1 ? mat[r1*132 + base + c] : 0.f;
            }
            #pragma unroll
            for (int kk = 0; kk < 16; ++kk) {
                float d   = rlane(a0[kk], kk);      // readlane -> sgpr broadcast
                float rdk = rsqrtf(d);
                float sq  = d * rdk;
                a0[kk] = (ln == kk) ? sq : a0[kk] * rdk;
                a1[kk] *= rdk;
                #pragma unroll
                for (int j = kk+1; j < 16; ++j) {
                    float ljv = rlane(a0[kk], j);
                    a0[j] = fmaf(-a0[kk], ljv, a0[j]);
                    a1[j] = fmaf(-a1[kk], ljv, a1[j]);
                }
            }
            #pragma unroll
            for (int c = 0; c < 16; ++c) {
                if (h0) mat[r0*132 + base + c] = a0[c];
                if (h1) mat[r1*132 + base + c] = a1[c];
            }
        }
        __syncthreads();
        int S = 112 - base;
        if (S > 0) {
            int T = S >> 2, nb = base + 16;
            for (int t = tid; t < T*T; t += 256) {
                int ti = t / T, tj = t - ti*T;
                if (tj <= ti) {
                    int i0 = nb + ti*4, j0 = nb + tj*4;
                    float ac[4][4];
                    #pragma unroll
                    for (int r = 0; r < 4; ++r)
                        #pragma unroll
                        for (int s = 0; s < 4; ++s) ac[r][s] = mat[(i0+r)*132 + j0 + s];
                    #pragma unroll
                    for (int c4 = 0; c4 < 4; ++c4) {
                        float4 av[4], bv[4];
                        #pragma unroll
                        for (int r = 0; r < 4; ++r) {
                            av[r] = *(const float4*)&mat[(i0+r)*132 + base + c4*4];
                            bv[r] = *(const float4*)&mat[(j0+r)*132 + base + c4*4];
                        }
                        #pragma unroll
                        for (int r = 0; r < 4; ++r)
                            #pragma unroll
                            for (int s = 0; s < 4; ++s)
                                ac[r][s] -= av[r].x*bv[s].x + av[r].y*bv[s].y
                                          + av[r].z*bv[s].z + av[r].w*bv[s].w;
                    }
                    #pragma unroll
                    for (int r = 0; r < 4; ++r)
                        #pragma unroll
                        for (int s = 0; s < 4; ++s) mat[(i0+r)*132 + j0 + s] = ac[r][s];
                }
            }
        }
        __syncthreads();
    }
}

__device__ __forceinline__ void dev_dinv(const float* mat, float* dinvb, int tid)
{
    int wv = tid >> 6, ln = tid & 63;
    if (ln < 16) {
        int c = ln;
        for (int half = 0; half < 2; ++half) {
            int bd = wv + half*4, base = bd*16;
            float x[16];
            #pragma unroll
            for (int i = 0; i < 16; ++i) {
                float dii = mat[(base+i)*132 + base + i];
                float s = 0.f;
                #pragma unroll
                for (int j = 0; j < i; ++j) s += mat[(base+i)*132 + base + j] * x[j];
                float v;
                if (i < c) v = 0.f;
                else if (i == c) v = 1.0f / dii;
                else v = -s / dii;
                x[i] = v;
            }
            #pragma unroll
            for (int i = 0; i < 16; ++i) dinvb[bd*256 + i*16 + c] = x[i];
        }
    }
    __syncthreads();
}

template<int C>
__device__ __forceinline__ void dev_solve(const float* mat, const float* dinvb,
                                          float* tmp, float* rhs, int tid)
{
    const int AT = 16*C;
    int r = tid / C, cc = tid % C;
    for (int bi = 0; bi < 8; ++bi) {
        float acc = 0.f;
        if (tid < AT) {
            acc = rhs[(bi*16+r)*C + cc];
            for (int bk = 0; bk < bi; ++bk) {
                #pragma unroll
                for (int kk = 0; kk < 16; ++kk)
                    acc -= mat[(bi*16+r)*132 + bk*16+kk] * rhs[(bk*16+kk)*C + cc];
            }
        }
        __syncthreads();
        if (tid < AT) tmp[r*C + cc] = acc;
        __syncthreads();
        if (tid < AT) {
            float w = 0.f;
            #pragma unroll
            for (int kk = 0; kk < 16; ++kk)
                w += dinvb[bi*256 + r*16 + kk] * tmp[kk*C + cc];
            rhs[(bi*16+r)*C + cc] = w;
        }
        __syncthreads();
    }
}

// ============ K3: psi2 (blocks 0-255, atomic) + chol(Kuu) (block 256) ============
__global__ __launch_bounds__(256) void psi2chol_kernel(
    const _Float16* __restrict__ Zh, const float* __restrict__ r_g,
    const _Float16* __restrict__ bh, float* __restrict__ psi2,
    const float* __restrict__ Kuu, float* __restrict__ Lg,
    float* __restrict__ Dinvg, float* __restrict__ scalars)
{
    __shared__ float mat[128*132];
    __shared__ float dinvb[8*256];
    __shared__ float red[256];
    __shared__ float pacc[4][64][4];
    int tid = threadIdx.x;
    if (blockIdx.x < 256) {
        int w = tid >> 6, l = tid & 63, lm = l & 15, lg = l >> 4;
        int tile = blockIdx.x & 63, nq = blockIdx.x >> 6;
        int mt = tile >> 3, kt = tile & 7;
        half8 Bf = ((const half8*)Zh)[(kt*16 + lm)*4 + lg];
        half8 Zm = ((const half8*)Zh)[(mt*16 + lm)*4 + lg];
        f32x4 z4; z4[0]=0.f; z4[1]=0.f; z4[2]=0.f; z4[3]=0.f;
        f32x4 acc = z4;
        int n0 = nq*1024 + w*256;
        for (int n = n0; n < n0+256; ++n) {
            half8 bf = ((const half8*)bh)[n*4 + lg];
            half8 A = Zm * bf;
            f32x4 rm = *(const f32x4*)(r_g + n*MM + mt*16 + lg*4);
            float rk = r_g[n*MM + kt*16 + lm];
            f32x4 p = __builtin_amdgcn_mfma_f32_16x16x32_f16(A, Bf, z4, 0, 0, 0);
            acc[0] += fexp2(p[0] + rm[0] + rk);
            acc[1] += fexp2(p[1] + rm[1] + rk);
            acc[2] += fexp2(p[2] + rm[2] + rk);
            acc[3] += fexp2(p[3] + rm[3] + rk);
        }
        #pragma unroll
        for (int j = 0; j < 4; ++j) pacc[w][l][j] = acc[j];
        __syncthreads();
        if (w == 0) {
            #pragma unroll
            for (int j = 0; j < 4; ++j) {
                float s = pacc[0][l][j] + pacc[1][l][j] + pacc[2][l][j] + pacc[3][l][j];
                atomicAdd(&psi2[(mt*16 + lg*4 + j)*MM + kt*16 + lm], s);
            }
        }
    } else {
        for (int e = tid; e < 16384; e += 256) mat[(e>>7)*132 + (e&127)] = Kuu[e];
        __syncthreads();
        dev_chol(mat, tid);
        float ld = 0.f;
        if (tid < 128) ld = logf(mat[tid*132 + tid]);
        red[tid] = ld; __syncthreads();
        for (int s = 128; s; s >>= 1) { if (tid < s) red[tid] += red[tid+s]; __syncthreads(); }
        if (tid == 0) scalars[0] = red[0];
        dev_dinv(mat, dinvb, tid);
        for (int e = tid; e < 16384; e += 256) Lg[e] = mat[(e>>7)*132 + (e&127)];
        for (int e = tid; e < 2048; e += 256) Dinvg[e] = dinvb[e];
    }
}

// ============ K4: block0 = chol(G)+Y-solve; blocks 1-16 = W = L^-1 psi2 ============
__global__ __launch_bounds__(256) void cholG_kernel(
    const float* __restrict__ Kuu, const float* __restrict__ psi2,
    const float* __restrict__ Yp, const float* __restrict__ Lg,
    const float* __restrict__ Dinvg,
    float* __restrict__ Wg, float* __restrict__ scalars)
{
    __shared__ float mat[128*132];
    __shared__ float dinvb[8*256];
    __shared__ float rhs[128*8];
    __shared__ float tmp[16*8];
    __shared__ float red[256];
    int tid = threadIdx.x;
    if (blockIdx.x == 0) {
        for (int e = tid; e < 16384; e += 256)
            mat[(e>>7)*132 + (e&127)] = Kuu[e] + (1.0f/SIG2)*psi2[e];
        __syncthreads();
        dev_chol(mat, tid);
        float ld = 0.f;
        if (tid < 128) ld = logf(mat[tid*132 + tid]);
        red[tid] = ld; __syncthreads();
        for (int s = 128; s; s >>= 1) { if (tid < s) red[tid] += red[tid+s]; __syncthreads(); }
        if (tid == 0) scalars[1] = red[0];
        dev_dinv(mat, dinvb, tid);
        for (int e = tid; e < 512; e += 256) {
            float s = 0.f;
            for (int b = 0; b < 128; ++b) s += Yp[b*512 + e];
            rhs[e] = s;
        }
        __syncthreads();
        dev_solve<4>(mat, dinvb, tmp, rhs, tid);
        float c2 = 0.f;
        for (int e = tid; e < 512; e += 256) { float v = rhs[e]; c2 += v*v; }
        red[tid] = c2; __syncthreads();
        for (int s = 128; s; s >>= 1) { if (tid < s) red[tid] += red[tid+s]; __syncthreads(); }
        if (tid == 0) scalars[2] = red[0];
    } else {
        int c0 = (blockIdx.x - 1) * 8;
        for (int e = tid; e < 16384; e += 256) mat[(e>>7)*132 + (e&127)] = Lg[e];
        for (int e = tid; e < 2048; e += 256) dinvb[e] = Dinvg[e];
        for (int e = tid; e < 1024; e += 256)
            rhs[e] = psi2[(e>>3)*MM + c0 + (e&7)];
        __syncthreads();
        dev_solve<8>(mat, dinvb, tmp, rhs, tid);
        for (int e = tid; e < 1024; e += 256) Wg[(e>>3)*MM + c0 + (e&7)] = rhs[e];
    }
}

// ============ K5: trace partials + last-block final assembly ============
__global__ __launch_bounds__(256) void trace_kernel(
    const float* __restrict__ Lg, const float* __restrict__ Dinvg,
    const float* __restrict__ Wg, const float* __restrict__ varp,
    const float* __restrict__ sumsP, float* __restrict__ scalars,
    int* __restrict__ cnt, float* __restrict__ out)
{
    __shared__ float mat[128*132];
    __shared__ float dinvb[8*256];
    __shared__ float rhs[128*8];
    __shared__ float tmp[16*8];
    int tid = threadIdx.x;
    int c0 = blockIdx.x * 8;
    for (int e = tid; e < 16384; e += 256) mat[(e>>7)*132 + (e&127)] = Lg[e];
    for (int e = tid; e < 2048; e += 256) dinvb[e] = Dinvg[e];
    for (int e = tid; e < 1024; e += 256)
        rhs[e] = Wg[(c0 + (e&7))*MM + (e>>3)];
    __syncthreads();
    dev_solve<8>(mat, dinvb, tmp, rhs, tid);
    if (tid == 0) {
        float s = 0.f;
        #pragma unroll
        for (int cc = 0; cc < 8; ++cc) s += rhs[(c0+cc)*8 + cc];
        atomicAdd(&scalars[3], s);
        __threadfence();
        int old = atomicAdd(cnt, 1);
        if (old == 15) {
            float tr_raw = atomicAdd(&scalars[3], 0.0f);   // L2-coherent read
            float s1=0.f, s2=0.f, s3=0.f;
            for (int b = 0; b < 16; ++b) {
                s1 += sumsP[b*3+0]; s2 += sumsP[b*3+1]; s3 += sumsP[b*3+2];
            }
            float var = varp[0];
            float trAAT   = tr_raw / SIG2;
            float logdetB = 2.0f * (scalars[1] - scalars[0]);
            float sumc2   = scalars[2] / (SIG2*SIG2);
            float psi0    = (float)NN * var;
            const float LOG2PI = 1.837877066409345f;
            float NQf = (float)NQ;
            float bound = -0.5f*NQf*(LOG2PI + logf(SIG2));
            bound += -0.5f/SIG2 * s1;
            bound += -0.5f*(float)QQ*(psi0/SIG2 - trAAT);
            bound += -0.5f*(float)QQ*logdetB;
            bound += 0.5f*sumc2;
            bound += 0.5f*s2 + 0.5f*NQf*LOG2PI;
            bound += -(float)(LTT*QQ)*LOG2PI - 0.5f*s3;
            out[0] = bound;
        }
    }
}

extern "C" void kernel_launch(void* const* d_in, const int* in_sizes, int n_in,
                              void* d_out, int out_size, void* d_ws, size_t ws_size,
                              hipStream_t stream)
{
    (void)in_sizes; (void)n_in; (void)out_size; (void)ws_size;
    const float* Xm   = (const float*)d_in[0];
    const float* Xv   = (const float*)d_in[1];
    const float* Zg   = (const float*)d_in[2];
    const float* ls   = (const float*)d_in[3];
    const float* varp = (const float*)d_in[4];

    float* p = (float*)d_ws;
    float4*   pk4   = (float4*)p;       p += NN*DD*4;
    float*    r_g   = p;                p += NN*MM;
    float*    Yp    = p;                p += 128*512;
    _Float16* bh    = (_Float16*)p;     p += NN*DD/2;
    _Float16* Zh    = (_Float16*)p;     p += MM*DD/2;
    float*    L1p   = p;                p += NN;
    float*    bbp   = p;                p += NN;
    float*    sp    = p;                p += MM;
    float*    Kuu   = p;                p += MM*MM;
    float*    Lg    = p;                p += MM*MM;
    float*    Dinvg = p;                p += 2048;
    float*    Wg    = p;                p += MM*MM;
    float*    psi2  = p;                p += MM*MM;
    float*    sumsP = p;                p += 64;
    float*    scalars = p;              p += 8;
    int*      cnt   = (int*)p;          p += 4;

    hipMemsetAsync(psi2, 0, MM*MM*sizeof(float), stream);
    hipMemsetAsync(scalars+3, 0, sizeof(float), stream);
    hipMemsetAsync(cnt, 0, sizeof(int), stream);

    prepstatic_kernel<<<81, 256, 0, stream>>>(Xm, Xv, Zg, ls, varp,
                                              pk4, bh, L1p, bbp, sumsP, Kuu, sp, Zh);
    k1_kernel<<<128, 256, 0, stream>>>(Xm, Zg, pk4, L1p, bbp, sp, r_g, Yp);
    psi2chol_kernel<<<257, 256, 0, stream>>>(Zh, r_g, bh, psi2, Kuu, Lg, Dinvg, scalars);
    cholG_kernel<<<17, 256, 0, stream>>>(Kuu, psi2, Yp, Lg, Dinvg, Wg, scalars);
    trace_kernel<<<16, 256, 0, stream>>>(Lg, Dinvg, Wg, varp, sumsP, scalars, cnt, (float*)d_out);
}

// Round 5
// 285.060 us; speedup vs baseline: 3.1483x; 1.0014x over previous
//
#include <hip/hip_runtime.h>

#define NN   4096
#define NQ   (NN*4)
#define QQ   4
#define LTT  8
#define DD   32
#define MM   128
#define SIG2 0.001f
#define JIT  1e-5f
#define LOG2E 1.4426950408889634f

typedef _Float16 half8 __attribute__((ext_vector_type(8)));
typedef float    f32x4 __attribute__((ext_vector_type(4)));

__device__ __forceinline__ float fexp2(float x) { return exp2f(x); }

__device__ __forceinline__ float rlane(float v, int l) {
    return __uint_as_float(__builtin_amdgcn_readlane(__float_as_uint(v), l));
}

// ============ prep (blocks 0-15) + Kuu (16-79) + sp/Zh/zeroing (80) ============
__global__ __launch_bounds__(256) void prepstatic_kernel(
    const float* __restrict__ Xm, const float* __restrict__ Xv,
    const float* __restrict__ Zg, const float* __restrict__ ls,
    const float* __restrict__ varp,
    float4* __restrict__ pk4, _Float16* __restrict__ bh,
    float* __restrict__ L1p, float* __restrict__ bbp, float* __restrict__ sumsP,
    float* __restrict__ Kuu, float* __restrict__ sp, _Float16* __restrict__ Zh,
    float* __restrict__ Yg, float* __restrict__ scalars, int* __restrict__ cnt)
{
    int b = blockIdx.x, tid = threadIdx.x;
    if (b < 16) {
        __shared__ float ra[256], rb[256], rc[256];
        int n = b*256 + tid;
        float var = varp[0];
        float slog2 = 0.f, slog1 = 0.f, T1 = 0.f, c0 = 0.f;
        #pragma unroll 8
        for (int q = 0; q < DD; ++q) {
            float xm = Xm[n*QQ + q];
            float xv = Xv[n*QQ + q];
            float l  = ls[q];
            float l2 = l*l;
            float a    = 1.0f / (2.0f*xv + l2);
            float dinv = 1.0f / (l2 + xv);
            float4 v;
            v.x = LOG2E * a * xm;
            v.y = LOG2E * (-0.25f * a);
            v.z = dinv;
            v.w = -2.0f * dinv * xm;
            pk4[n*DD + q] = v;
            bh[n*DD + q] = (_Float16)(0.5f * LOG2E * (1.0f/l2 - a));
            slog2 += log1pf(2.0f*xv/l2);
            slog1 += log1pf(xv/l2);
            T1    += a*xm*xm;
            c0    += dinv*xm*xm;
        }
        L1p[n] = 0.5f * LOG2E * (2.0f*logf(var) - 0.5f*slog2 - T1);
        bbp[n] = logf(var) - 0.5f*slog1 - 0.5f*c0;
        float s1 = 0.f, s2 = 0.f, s3 = 0.f;
        #pragma unroll
        for (int c = 0; c < QQ; ++c) {
            float mo = Xm[(n+LTT)*QQ + c];
            float vo = Xv[(n+LTT)*QQ + c];
            s1 += vo + mo*mo;
            s2 += logf(vo);
        }
        if (n < LTT) {
            #pragma unroll
            for (int c = 0; c < QQ; ++c) {
                float mb = Xm[n*QQ+c], vb = Xv[n*QQ+c];
                s3 += mb*mb + vb;
            }
        }
        ra[tid]=s1; rb[tid]=s2; rc[tid]=s3;
        __syncthreads();
        for (int s = 128; s; s >>= 1) {
            if (tid < s) { ra[tid]+=ra[tid+s]; rb[tid]+=rb[tid+s]; rc[tid]+=rc[tid+s]; }
            __syncthreads();
        }
        if (tid == 0) { sumsP[b*3+0]=ra[0]; sumsP[b*3+1]=rb[0]; sumsP[b*3+2]=rc[0]; }
    } else if (b < 80) {
        int idx = (b-16)*256 + tid;
        int i = idx >> 7, j = idx & 127;
        float var = varp[0];
        float s = 0.f;
        for (int q = 0; q < DD; ++q) {
            float l = ls[q];
            float d = (Zg[i*DD+q] - Zg[j*DD+q]) / l;
            s += d*d;
        }
        float v = var * __expf(-0.5f*s);
        if (i == j) v += JIT;
        Kuu[idx] = v;
    } else {
        if (tid < MM) {
            float s = 0.f;
            for (int q = 0; q < DD; ++q) {
                float l = ls[q]; float z = Zg[tid*DD+q];
                s += z*z / (4.0f*l*l);
            }
            sp[tid] = LOG2E * s;
        }
        for (int e = tid; e < MM*DD; e += 256) Zh[e] = (_Float16)Zg[e];
        // zero accumulators used later
        for (int e = tid; e < 512; e += 256) Yg[e] = 0.f;
        if (tid < 8) scalars[tid] = 0.f;
        if (tid == 0) *cnt = 0;
    }
}

// ============ k1: r[n,m] + Yg atomics + psi2 zeroing ============
__global__ __launch_bounds__(256) void k1_kernel(
    const float* __restrict__ Xm, const float* __restrict__ Zg,
    const float4* __restrict__ pk4, const float* __restrict__ L1p,
    const float* __restrict__ bbp, const float* __restrict__ sp,
    float* __restrict__ r_g, float* __restrict__ Yg, float* __restrict__ psi2)
{
    __shared__ float Zl[MM*33];
    __shared__ float yredl[MM*QQ];
    int tid = threadIdx.x;
    // zero this block's psi2 slice (psi2 atomics happen next kernel)
    { int e = blockIdx.x*128 + tid; if (tid < 128) psi2[e] = 0.f; }
    for (int e = tid; e < MM*DD; e += 256)
        Zl[(e>>5)*33 + (e&31)] = Zg[e];
    __syncthreads();
    int m = tid & 127, half = tid >> 7;
    float zr[DD];
    #pragma unroll
    for (int q = 0; q < DD; ++q) zr[q] = Zl[m*33 + q];
    float sm = sp[m];
    float y0=0.f, y1=0.f, y2=0.f, y3=0.f;
    int n0 = blockIdx.x*32 + half*16;
    for (int i = 0; i < 16; ++i) {
        int n = n0 + i;
        float L1n = L1p[n], bbn = bbp[n];
        const float4* pkn = pk4 + n*DD;
        float racc = 0.f, q1 = 0.f;
        #pragma unroll
        for (int q = 0; q < DD; ++q) {
            float4 v = pkn[q];
            float z = zr[q];
            racc = fmaf(v.x, z, racc);
            racc = fmaf(v.y, z*z, racc);
            float t = fmaf(v.z, z, v.w);
            q1 = fmaf(t, z, q1);
        }
        r_g[n*MM + m] = L1n + racc - sm;
        float p1 = __expf(fmaf(-0.5f, q1, bbn));
        float4 xo = *(const float4*)(Xm + (LTT+n)*QQ);
        y0 = fmaf(p1, xo.x, y0); y1 = fmaf(p1, xo.y, y1);
        y2 = fmaf(p1, xo.z, y2); y3 = fmaf(p1, xo.w, y3);
    }
    if (half == 0) {
        yredl[m*4+0]=y0; yredl[m*4+1]=y1; yredl[m*4+2]=y2; yredl[m*4+3]=y3;
    }
    __syncthreads();
    if (half == 1) {
        yredl[m*4+0]+=y0; yredl[m*4+1]+=y1; yredl[m*4+2]+=y2; yredl[m*4+3]+=y3;
    }
    __syncthreads();
    for (int e = tid; e < 512; e += 256) atomicAdd(&Yg[e], yredl[e]);
}

// ============ shared linalg device functions (LDS stride 132) ============
template<int NT>
__device__ __forceinline__ void dev_chol(float* mat, int tid)
{
    int wv = tid >> 6, ln = tid & 63;
    for (int p = 0; p < 8; ++p) {
        int base = p*16;
        if (wv == 0) {
            int r0 = base + ln, r1 = r0 + 64;
            bool h0 = r0 < 128, h1 = r1 < 128;
            float a0[16], a1[16];
            #pragma unroll
            for (int c = 0; c < 16; ++c) {
                a0[c] = h0 ? mat[r0*132 + base + c] : 0.f;
                a1[c] = h1 ? mat[r1*132 + base + c] : 0.f;
            }
            #pragma unroll
            for (int kk = 0; kk < 16; ++kk) {
                float d   = rlane(a0[kk], kk);
                float rdk = rsqrtf(d);
                float sq  = d * rdk;
                a0[kk] = (ln == kk) ? sq : a0[kk] * rdk;
                a1[kk] *= rdk;
                #pragma unroll
                for (int j = kk+1; j < 16; ++j) {
                    float ljv = rlane(a0[kk], j);
                    a0[j] = fmaf(-a0[kk], ljv, a0[j]);
                    a1[j] = fmaf(-a1[kk], ljv, a1[j]);
                }
            }
            #pragma unroll
            for (int c = 0; c < 16; ++c) {
                if (h0) mat[r0*132 + base + c] = a0[c];
                if (h1) mat[r1*132 + base + c] = a1[c];
            }
        }
        __syncthreads();
        int S = 112 - base;
        if (S > 0) {
            int T = S >> 2, nb = base + 16;
            for (int t = tid; t < T*T; t += NT) {
                int ti = t / T, tj = t - ti*T;
                if (tj <= ti) {
                    int i0 = nb + ti*4, j0 = nb + tj*4;
                    float ac[4][4];
                    #pragma unroll
                    for (int r = 0; r < 4; ++r)
                        #pragma unroll
                        for (int s = 0; s < 4; ++s) ac[r][s] = mat[(i0+r)*132 + j0 + s];
                    #pragma unroll
                    for (int c4 = 0; c4 < 4; ++c4) {
                        float4 av[4], bv[4];
                        #pragma unroll
                        for (int r = 0; r < 4; ++r) {
                            av[r] = *(const float4*)&mat[(i0+r)*132 + base + c4*4];
                            bv[r] = *(const float4*)&mat[(j0+r)*132 + base + c4*4];
                        }
                        #pragma unroll
                        for (int r = 0; r < 4; ++r)
                            #pragma unroll
                            for (int s = 0; s < 4; ++s)
                                ac[r][s] -= av[r].x*bv[s].x + av[r].y*bv[s].y
                                          + av[r].z*bv[s].z + av[r].w*bv[s].w;
                    }
                    #pragma unroll
                    for (int r = 0; r < 4; ++r)
                        #pragma unroll
                        for (int s = 0; s < 4; ++s) mat[(i0+r)*132 + j0 + s] = ac[r][s];
                }
            }
        }
        __syncthreads();
    }
}

template<int NT>
__device__ __forceinline__ void dev_dinv(const float* mat, float* dinvb, int tid)
{
    int wv = tid >> 6, ln = tid & 63;
    if (ln < 16) {
        int c = ln;
        for (int bd = wv; bd < 8; bd += NT/64) {
            int base = bd*16;
            float x[16];
            #pragma unroll
            for (int i = 0; i < 16; ++i) {
                float dii = mat[(base+i)*132 + base + i];
                float s = 0.f;
                #pragma unroll
                for (int j = 0; j < i; ++j) s += mat[(base+i)*132 + base + j] * x[j];
                float v;
                if (i < c) v = 0.f;
                else if (i == c) v = 1.0f / dii;
                else v = -s / dii;
                x[i] = v;
            }
            #pragma unroll
            for (int i = 0; i < 16; ++i) dinvb[bd*256 + i*16 + c] = x[i];
        }
    }
    __syncthreads();
}

template<int C>
__device__ __forceinline__ void dev_solve(const float* mat, const float* dinvb,
                                          float* tmp, float* rhs, int tid)
{
    const int AT = 16*C;
    int r = tid / C, cc = tid % C;
    for (int bi = 0; bi < 8; ++bi) {
        float acc = 0.f;
        if (tid < AT) {
            acc = rhs[(bi*16+r)*C + cc];
            for (int bk = 0; bk < bi; ++bk) {
                #pragma unroll
                for (int kk = 0; kk < 16; ++kk)
                    acc -= mat[(bi*16+r)*132 + bk*16+kk] * rhs[(bk*16+kk)*C + cc];
            }
        }
        __syncthreads();
        if (tid < AT) tmp[r*C + cc] = acc;
        __syncthreads();
        if (tid < AT) {
            float w = 0.f;
            #pragma unroll
            for (int kk = 0; kk < 16; ++kk)
                w += dinvb[bi*256 + r*16 + kk] * tmp[kk*C + cc];
            rhs[(bi*16+r)*C + cc] = w;
        }
        __syncthreads();
    }
}

// ============ K3: psi2 (blocks 0-127, 16 waves each) + chol(Kuu) (block 128) ============
__global__ __launch_bounds__(1024) void psi2chol_kernel(
    const _Float16* __restrict__ Zh, const float* __restrict__ r_g,
    const _Float16* __restrict__ bh, float* __restrict__ psi2,
    const float* __restrict__ Kuu, float* __restrict__ Lg,
    float* __restrict__ Dinvg, float* __restrict__ scalars)
{
    __shared__ float mat[128*132];
    __shared__ float dinvb[8*256];
    __shared__ float red[1024];
    float (*pacc)[64][4] = (float(*)[64][4])mat;   // psi2 blocks alias mat
    int tid = threadIdx.x;
    if (blockIdx.x < 128) {
        int w = tid >> 6, l = tid & 63, lm = l & 15, lg = l >> 4;
        int tile = blockIdx.x & 63, half = blockIdx.x >> 6;
        int mt = tile >> 3, kt = tile & 7;
        half8 Bf = ((const half8*)Zh)[(kt*16 + lm)*4 + lg];
        half8 Zm = ((const half8*)Zh)[(mt*16 + lm)*4 + lg];
        f32x4 z4; z4[0]=0.f; z4[1]=0.f; z4[2]=0.f; z4[3]=0.f;
        f32x4 acc = z4;
        int n0 = half*2048 + w*128;
        #pragma unroll 2
        for (int n = n0; n < n0+128; ++n) {
            half8 bf = ((const half8*)bh)[n*4 + lg];
            half8 A = Zm * bf;
            f32x4 rm = *(const f32x4*)(r_g + n*MM + mt*16 + lg*4);
            float rk = r_g[n*MM + kt*16 + lm];
            f32x4 p = __builtin_amdgcn_mfma_f32_16x16x32_f16(A, Bf, z4, 0, 0, 0);
            acc[0] += fexp2(p[0] + rm[0] + rk);
            acc[1] += fexp2(p[1] + rm[1] + rk);
            acc[2] += fexp2(p[2] + rm[2] + rk);
            acc[3] += fexp2(p[3] + rm[3] + rk);
        }
        #pragma unroll
        for (int j = 0; j < 4; ++j) pacc[w][l][j] = acc[j];
        __syncthreads();
        if (tid < 256) {
            int ll = tid >> 2, j = tid & 3;
            float s = 0.f;
            #pragma unroll
            for (int ww = 0; ww < 16; ++ww) s += pacc[ww][ll][j];
            int row = mt*16 + (ll >> 4)*4 + j;
            int col = kt*16 + (ll & 15);
            atomicAdd(&psi2[row*MM + col], s);
        }
    } else {
        for (int e = tid; e < 16384; e += 1024) mat[(e>>7)*132 + (e&127)] = Kuu[e];
        __syncthreads();
        dev_chol<1024>(mat, tid);
        float ld = (tid < 128) ? logf(mat[tid*132 + tid]) : 0.f;
        red[tid] = ld; __syncthreads();
        for (int s = 512; s; s >>= 1) { if (tid < s) red[tid] += red[tid+s]; __syncthreads(); }
        if (tid == 0) scalars[0] = red[0];
        dev_dinv<1024>(mat, dinvb, tid);
        for (int e = tid; e < 16384; e += 1024) Lg[e] = mat[(e>>7)*132 + (e&127)];
        for (int e = tid; e < 2048; e += 1024) Dinvg[e] = dinvb[e];
    }
}

// ============ K4: block0 = chol(G)+Y-solve; blocks 1-16 = W = L^-1 psi2 ============
__global__ __launch_bounds__(1024) void cholG_kernel(
    const float* __restrict__ Kuu, const float* __restrict__ psi2,
    const float* __restrict__ Yg, const float* __restrict__ Lg,
    const float* __restrict__ Dinvg,
    float* __restrict__ Wg, float* __restrict__ scalars)
{
    __shared__ float mat[128*132];
    __shared__ float dinvb[8*256];
    __shared__ float rhs[128*8];
    __shared__ float tmp[128];
    __shared__ float red[1024];
    int tid = threadIdx.x;
    if (blockIdx.x == 0) {
        for (int e = tid; e < 16384; e += 1024)
            mat[(e>>7)*132 + (e&127)] = Kuu[e] + (1.0f/SIG2)*psi2[e];
        __syncthreads();
        dev_chol<1024>(mat, tid);
        float ld = (tid < 128) ? logf(mat[tid*132 + tid]) : 0.f;
        red[tid] = ld; __syncthreads();
        for (int s = 512; s; s >>= 1) { if (tid < s) red[tid] += red[tid+s]; __syncthreads(); }
        if (tid == 0) scalars[1] = red[0];
        dev_dinv<1024>(mat, dinvb, tid);
        if (tid < 512) rhs[tid] = Yg[tid];
        __syncthreads();
        dev_solve<4>(mat, dinvb, tmp, rhs, tid);
        float c2 = 0.f;
        if (tid < 512) { float v = rhs[tid]; c2 = v*v; }
        red[tid] = c2; __syncthreads();
        for (int s = 512; s; s >>= 1) { if (tid < s) red[tid] += red[tid+s]; __syncthreads(); }
        if (tid == 0) scalars[2] = red[0];
    } else {
        int c0 = (blockIdx.x - 1) * 8;
        for (int e = tid; e < 16384; e += 1024) mat[(e>>7)*132 + (e&127)] = Lg[e];
        for (int e = tid; e < 2048; e += 1024) dinvb[e] = Dinvg[e];
        if (tid < 1024) { int e = tid; rhs[e] = psi2[(e>>3)*MM + c0 + (e&7)]; }
        __syncthreads();
        dev_solve<8>(mat, dinvb, tmp, rhs, tid);
        if (tid < 1024) { int e = tid; Wg[(e>>3)*MM + c0 + (e&7)] = rhs[e]; }
    }
}

// ============ K5: trace partials + last-block final assembly ============
__global__ __launch_bounds__(256) void trace_kernel(
    const float* __restrict__ Lg, const float* __restrict__ Dinvg,
    const float* __restrict__ Wg, const float* __restrict__ varp,
    const float* __restrict__ sumsP, float* __restrict__ scalars,
    int* __restrict__ cnt, float* __restrict__ out)
{
    __shared__ float mat[128*132];
    __shared__ float dinvb[8*256];
    __shared__ float rhs[128*8];
    __shared__ float tmp[128];
    int tid = threadIdx.x;
    int c0 = blockIdx.x * 8;
    for (int e = tid; e < 16384; e += 256) mat[(e>>7)*132 + (e&127)] = Lg[e];
    for (int e = tid; e < 2048; e += 256) dinvb[e] = Dinvg[e];
    for (int e = tid; e < 1024; e += 256)
        rhs[e] = Wg[(c0 + (e&7))*MM + (e>>3)];
    __syncthreads();
    dev_solve<8>(mat, dinvb, tmp, rhs, tid);
    if (tid == 0) {
        float s = 0.f;
        #pragma unroll
        for (int cc = 0; cc < 8; ++cc) s += rhs[(c0+cc)*8 + cc];
        atomicAdd(&scalars[3], s);
        __threadfence();
        int old = atomicAdd(cnt, 1);
        if (old == 15) {
            float tr_raw = atomicAdd(&scalars[3], 0.0f);
            float s1=0.f, s2=0.f, s3=0.f;
            for (int b = 0; b < 16; ++b) {
                s1 += sumsP[b*3+0]; s2 += sumsP[b*3+1]; s3 += sumsP[b*3+2];
            }
            float var = varp[0];
            float trAAT   = tr_raw / SIG2;
            float logdetB = 2.0f * (scalars[1] - scalars[0]);
            float sumc2   = scalars[2] / (SIG2*SIG2);
            float psi0    = (float)NN * var;
            const float LOG2PI = 1.837877066409345f;
            float NQf = (float)NQ;
            float bound = -0.5f*NQf*(LOG2PI + logf(SIG2));
            bound += -0.5f/SIG2 * s1;
            bound += -0.5f*(float)QQ*(psi0/SIG2 - trAAT);
            bound += -0.5f*(float)QQ*logdetB;
            bound += 0.5f*sumc2;
            bound += 0.5f*s2 + 0.5f*NQf*LOG2PI;
            bound += -(float)(LTT*QQ)*LOG2PI - 0.5f*s3;
            out[0] = bound;
        }
    }
}

extern "C" void kernel_launch(void* const* d_in, const int* in_sizes, int n_in,
                              void* d_out, int out_size, void* d_ws, size_t ws_size,
                              hipStream_t stream)
{
    (void)in_sizes; (void)n_in; (void)out_size; (void)ws_size;
    const float* Xm   = (const float*)d_in[0];
    const float* Xv   = (const float*)d_in[1];
    const float* Zg   = (const float*)d_in[2];
    const float* ls   = (const float*)d_in[3];
    const float* varp = (const float*)d_in[4];

    float* p = (float*)d_ws;
    float4*   pk4   = (float4*)p;       p += NN*DD*4;
    float*    r_g   = p;                p += NN*MM;
    _Float16* bh    = (_Float16*)p;     p += NN*DD/2;
    _Float16* Zh    = (_Float16*)p;     p += MM*DD/2;
    float*    L1p   = p;                p += NN;
    float*    bbp   = p;                p += NN;
    float*    sp    = p;                p += MM;
    float*    Kuu   = p;                p += MM*MM;
    float*    Lg    = p;                p += MM*MM;
    float*    Dinvg = p;                p += 2048;
    float*    Wg    = p;                p += MM*MM;
    float*    psi2  = p;                p += MM*MM;
    float*    Yg    = p;                p += 512;
    float*    sumsP = p;                p += 64;
    float*    scalars = p;              p += 8;
    int*      cnt   = (int*)p;          p += 4;

    prepstatic_kernel<<<81, 256, 0, stream>>>(Xm, Xv, Zg, ls, varp,
                                              pk4, bh, L1p, bbp, sumsP, Kuu, sp, Zh,
                                              Yg, scalars, cnt);
    k1_kernel<<<128, 256, 0, stream>>>(Xm, Zg, pk4, L1p, bbp, sp, r_g, Yg, psi2);
    psi2chol_kernel<<<129, 1024, 0, stream>>>(Zh, r_g, bh, psi2, Kuu, Lg, Dinvg, scalars);
    cholG_kernel<<<17, 1024, 0, stream>>>(Kuu, psi2, Yg, Lg, Dinvg, Wg, scalars);
    trace_kernel<<<16, 256, 0, stream>>>(Lg, Dinvg, Wg, varp, sumsP, scalars, cnt, (float*)d_out);
}

// Round 6
// 225.634 us; speedup vs baseline: 3.9774x; 1.2634x over previous
//
#include <hip/hip_runtime.h>

#define NN   4096
#define NQ   (NN*4)
#define QQ   4
#define LTT  8
#define DD   32
#define MM   128
#define SIG2 0.001f
#define JIT  1e-5f
#define LOG2E 1.4426950408889634f

typedef _Float16 half8 __attribute__((ext_vector_type(8)));
typedef float    f32x4 __attribute__((ext_vector_type(4)));

__device__ __forceinline__ float fexp2(float x) { return exp2f(x); }

__device__ __forceinline__ float rlane(float v, int l) {
    return __uint_as_float(__builtin_amdgcn_readlane(__float_as_uint(v), l));
}

// ============ prep (blocks 0-15) + Kuu (16-79) + sp/Zh/zeroing (80) ============
__global__ __launch_bounds__(256) void prepstatic_kernel(
    const float* __restrict__ Xm, const float* __restrict__ Xv,
    const float* __restrict__ Zg, const float* __restrict__ ls,
    const float* __restrict__ varp,
    float4* __restrict__ pk4, _Float16* __restrict__ bh,
    float* __restrict__ L1p, float* __restrict__ bbp, float* __restrict__ sumsP,
    float* __restrict__ Kuu, float* __restrict__ sp, _Float16* __restrict__ Zh,
    float* __restrict__ Yg, float* __restrict__ scalars, int* __restrict__ cnt)
{
    int b = blockIdx.x, tid = threadIdx.x;
    if (b < 16) {
        __shared__ float ra[256], rb[256], rc[256];
        int n = b*256 + tid;
        float var = varp[0];
        float slog2 = 0.f, slog1 = 0.f, T1 = 0.f, c0 = 0.f;
        #pragma unroll 8
        for (int q = 0; q < DD; ++q) {
            float xm = Xm[n*QQ + q];
            float xv = Xv[n*QQ + q];
            float l  = ls[q];
            float l2 = l*l;
            float a    = 1.0f / (2.0f*xv + l2);
            float dinv = 1.0f / (l2 + xv);
            float4 v;
            v.x = LOG2E * a * xm;
            v.y = LOG2E * (-0.25f * a);
            v.z = dinv;
            v.w = -2.0f * dinv * xm;
            pk4[n*DD + q] = v;
            bh[n*DD + q] = (_Float16)(0.5f * LOG2E * (1.0f/l2 - a));
            slog2 += log1pf(2.0f*xv/l2);
            slog1 += log1pf(xv/l2);
            T1    += a*xm*xm;
            c0    += dinv*xm*xm;
        }
        L1p[n] = 0.5f * LOG2E * (2.0f*logf(var) - 0.5f*slog2 - T1);
        bbp[n] = logf(var) - 0.5f*slog1 - 0.5f*c0;
        float s1 = 0.f, s2 = 0.f, s3 = 0.f;
        #pragma unroll
        for (int c = 0; c < QQ; ++c) {
            float mo = Xm[(n+LTT)*QQ + c];
            float vo = Xv[(n+LTT)*QQ + c];
            s1 += vo + mo*mo;
            s2 += logf(vo);
        }
        if (n < LTT) {
            #pragma unroll
            for (int c = 0; c < QQ; ++c) {
                float mb = Xm[n*QQ+c], vb = Xv[n*QQ+c];
                s3 += mb*mb + vb;
            }
        }
        ra[tid]=s1; rb[tid]=s2; rc[tid]=s3;
        __syncthreads();
        for (int s = 128; s; s >>= 1) {
            if (tid < s) { ra[tid]+=ra[tid+s]; rb[tid]+=rb[tid+s]; rc[tid]+=rc[tid+s]; }
            __syncthreads();
        }
        if (tid == 0) { sumsP[b*3+0]=ra[0]; sumsP[b*3+1]=rb[0]; sumsP[b*3+2]=rc[0]; }
    } else if (b < 80) {
        int idx = (b-16)*256 + tid;
        int i = idx >> 7, j = idx & 127;
        float var = varp[0];
        float s = 0.f;
        for (int q = 0; q < DD; ++q) {
            float l = ls[q];
            float d = (Zg[i*DD+q] - Zg[j*DD+q]) / l;
            s += d*d;
        }
        float v = var * __expf(-0.5f*s);
        if (i == j) v += JIT;
        Kuu[idx] = v;
    } else {
        if (tid < MM) {
            float s = 0.f;
            for (int q = 0; q < DD; ++q) {
                float l = ls[q]; float z = Zg[tid*DD+q];
                s += z*z / (4.0f*l*l);
            }
            sp[tid] = LOG2E * s;
        }
        for (int e = tid; e < MM*DD; e += 256) Zh[e] = (_Float16)Zg[e];
        for (int e = tid; e < 512; e += 256) Yg[e] = 0.f;
        if (tid < 8) scalars[tid] = 0.f;
        if (tid == 0) *cnt = 0;
    }
}

// ============ k1: r[n,m] + Yg atomics + psi2 zeroing ============
__global__ __launch_bounds__(256) void k1_kernel(
    const float* __restrict__ Xm, const float* __restrict__ Zg,
    const float4* __restrict__ pk4, const float* __restrict__ L1p,
    const float* __restrict__ bbp, const float* __restrict__ sp,
    float* __restrict__ r_g, float* __restrict__ Yg, float* __restrict__ psi2)
{
    __shared__ float Zl[MM*33];
    __shared__ float yredl[MM*QQ];
    int tid = threadIdx.x;
    { int e = blockIdx.x*128 + tid; if (tid < 128) psi2[e] = 0.f; }
    for (int e = tid; e < MM*DD; e += 256)
        Zl[(e>>5)*33 + (e&31)] = Zg[e];
    __syncthreads();
    int m = tid & 127, half = tid >> 7;
    float zr[DD];
    #pragma unroll
    for (int q = 0; q < DD; ++q) zr[q] = Zl[m*33 + q];
    float sm = sp[m];
    float y0=0.f, y1=0.f, y2=0.f, y3=0.f;
    int n0 = blockIdx.x*32 + half*16;
    for (int i = 0; i < 16; ++i) {
        int n = n0 + i;
        float L1n = L1p[n], bbn = bbp[n];
        const float4* pkn = pk4 + n*DD;
        float racc = 0.f, q1 = 0.f;
        #pragma unroll
        for (int q = 0; q < DD; ++q) {
            float4 v = pkn[q];
            float z = zr[q];
            racc = fmaf(v.x, z, racc);
            racc = fmaf(v.y, z*z, racc);
            float t = fmaf(v.z, z, v.w);
            q1 = fmaf(t, z, q1);
        }
        r_g[n*MM + m] = L1n + racc - sm;
        float p1 = __expf(fmaf(-0.5f, q1, bbn));
        float4 xo = *(const float4*)(Xm + (LTT+n)*QQ);
        y0 = fmaf(p1, xo.x, y0); y1 = fmaf(p1, xo.y, y1);
        y2 = fmaf(p1, xo.z, y2); y3 = fmaf(p1, xo.w, y3);
    }
    if (half == 0) {
        yredl[m*4+0]=y0; yredl[m*4+1]=y1; yredl[m*4+2]=y2; yredl[m*4+3]=y3;
    }
    __syncthreads();
    if (half == 1) {
        yredl[m*4+0]+=y0; yredl[m*4+1]+=y1; yredl[m*4+2]+=y2; yredl[m*4+3]+=y3;
    }
    __syncthreads();
    for (int e = tid; e < 512; e += 256) atomicAdd(&Yg[e], yredl[e]);
}

// ============ linalg device functions, 256 threads, LDS stride 132 ============
__device__ __forceinline__ void dev_chol(float* mat, int tid)
{
    int wv = tid >> 6, ln = tid & 63;
    for (int p = 0; p < 8; ++p) {
        int base = p*16;
        if (wv == 0) {
            int r0 = base + ln, r1 = r0 + 64;
            bool h0 = r0 < 128, h1 = r1 < 128;
            float a0[16], a1[16];
            #pragma unroll
            for (int c = 0; c < 16; ++c) {
                a0[c] = h0 ? mat[r0*132 + base + c] : 0.f;
                a1[c] = h1 ? mat[r1*132 + base + c] : 0.f;
            }
            #pragma unroll
            for (int kk = 0; kk < 16; ++kk) {
                float d   = rlane(a0[kk], kk);
                float rdk = rsqrtf(d);
                float sq  = d * rdk;
                a0[kk] = (ln == kk) ? sq : a0[kk] * rdk;
                a1[kk] *= rdk;
                #pragma unroll
                for (int j = kk+1; j < 16; ++j) {
                    float ljv = rlane(a0[kk], j);
                    a0[j] = fmaf(-a0[kk], ljv, a0[j]);
                    a1[j] = fmaf(-a1[kk], ljv, a1[j]);
                }
            }
            #pragma unroll
            for (int c = 0; c < 16; ++c) {
                if (h0) mat[r0*132 + base + c] = a0[c];
                if (h1) mat[r1*132 + base + c] = a1[c];
            }
        }
        __syncthreads();
        int S = 112 - base;
        if (S > 0) {
            int T = S >> 2, nb = base + 16;
            int nT = (T*(T+1)) >> 1;
            for (int t = tid; t < nT; t += 256) {
                int ti = (int)(0.5f*(sqrtf(8.f*(float)t + 1.f) - 1.f));
                if ((ti+1)*(ti+2)/2 <= t) ++ti;
                else if (ti*(ti+1)/2 > t) --ti;
                int tj = t - ((ti*(ti+1))>>1);
                int i0 = nb + ti*4, j0 = nb + tj*4;
                float ac[4][4];
                #pragma unroll
                for (int r = 0; r < 4; ++r)
                    #pragma unroll
                    for (int s = 0; s < 4; ++s) ac[r][s] = mat[(i0+r)*132 + j0 + s];
                #pragma unroll
                for (int c4 = 0; c4 < 4; ++c4) {
                    float4 av[4], bv[4];
                    #pragma unroll
                    for (int r = 0; r < 4; ++r) {
                        av[r] = *(const float4*)&mat[(i0+r)*132 + base + c4*4];
                        bv[r] = *(const float4*)&mat[(j0+r)*132 + base + c4*4];
                    }
                    #pragma unroll
                    for (int r = 0; r < 4; ++r)
                        #pragma unroll
                        for (int s = 0; s < 4; ++s)
                            ac[r][s] -= av[r].x*bv[s].x + av[r].y*bv[s].y
                                      + av[r].z*bv[s].z + av[r].w*bv[s].w;
                }
                #pragma unroll
                for (int r = 0; r < 4; ++r)
                    #pragma unroll
                    for (int s = 0; s < 4; ++s) mat[(i0+r)*132 + j0 + s] = ac[r][s];
            }
        }
        __syncthreads();
    }
}

__device__ __forceinline__ void dev_dinv(const float* mat, float* dinvb, int tid)
{
    int wv = tid >> 6, ln = tid & 63;
    if (ln < 16) {
        int c = ln;
        for (int bd = wv; bd < 8; bd += 4) {
            int base = bd*16;
            float x[16];
            #pragma unroll
            for (int i = 0; i < 16; ++i) {
                float dii = mat[(base+i)*132 + base + i];
                float s = 0.f;
                #pragma unroll
                for (int j = 0; j < i; ++j) s += mat[(base+i)*132 + base + j] * x[j];
                float v;
                if (i < c) v = 0.f;
                else if (i == c) v = 1.0f / dii;
                else v = -s / dii;
                x[i] = v;
            }
            #pragma unroll
            for (int i = 0; i < 16; ++i) dinvb[bd*256 + i*16 + c] = x[i];
        }
    }
    __syncthreads();
}

template<int C>
__device__ __forceinline__ void dev_solve(const float* mat, const float* dinvb,
                                          float* tmp, float* rhs, int tid)
{
    const int AT = 16*C;
    int r = tid / C, cc = tid % C;
    for (int bi = 0; bi < 8; ++bi) {
        float acc = 0.f;
        if (tid < AT) {
            acc = rhs[(bi*16+r)*C + cc];
            for (int bk = 0; bk < bi; ++bk) {
                #pragma unroll
                for (int kk = 0; kk < 16; ++kk)
                    acc -= mat[(bi*16+r)*132 + bk*16+kk] * rhs[(bk*16+kk)*C + cc];
            }
        }
        __syncthreads();
        if (tid < AT) tmp[r*C + cc] = acc;
        __syncthreads();
        if (tid < AT) {
            float w = 0.f;
            #pragma unroll
            for (int kk = 0; kk < 16; ++kk)
                w += dinvb[bi*256 + r*16 + kk] * tmp[kk*C + cc];
            rhs[(bi*16+r)*C + cc] = w;
        }
        __syncthreads();
    }
}

// backward solve L^T y = rhs (mat holds L, dinvb holds Dinv blocks of L)
template<int C>
__device__ __forceinline__ void dev_bsolve(const float* mat, const float* dinvb,
                                           float* tmp, float* rhs, int tid)
{
    const int AT = 16*C;
    int r = tid / C, cc = tid % C;
    for (int bi = 7; bi >= 0; --bi) {
        float acc = 0.f;
        if (tid < AT) {
            acc = rhs[(bi*16+r)*C + cc];
            for (int bj = bi+1; bj < 8; ++bj) {
                #pragma unroll
                for (int kk = 0; kk < 16; ++kk)
                    acc -= mat[(bj*16+kk)*132 + bi*16 + r] * rhs[(bj*16+kk)*C + cc];
            }
        }
        __syncthreads();
        if (tid < AT) tmp[r*C + cc] = acc;
        __syncthreads();
        if (tid < AT) {
            float w = 0.f;
            #pragma unroll
            for (int kk = 0; kk < 16; ++kk)
                w += dinvb[bi*256 + kk*16 + r] * tmp[kk*C + cc];   // Dinv^T
            rhs[(bi*16+r)*C + cc] = w;
        }
        __syncthreads();
    }
}

// ============ K3: block0 = chol(Kuu); blocks 1-512 = psi2 (LDS-staged) ============
__global__ __launch_bounds__(256) void psi2chol_kernel(
    const _Float16* __restrict__ Zh, const float* __restrict__ r_g,
    const _Float16* __restrict__ bh, float* __restrict__ psi2,
    const float* __restrict__ Kuu, float* __restrict__ Lg,
    float* __restrict__ Dinvg, float* __restrict__ scalars)
{
    __shared__ float shm[19200];   // 76.8 KB -> 2 blocks/CU
    int tid = threadIdx.x;
    if (blockIdx.x == 0) {
        float* mat   = shm;
        float* dinvb = shm + 16896;
        float* red   = shm + 18944;
        for (int e = tid; e < 16384; e += 256) mat[(e>>7)*132 + (e&127)] = Kuu[e];
        __syncthreads();
        dev_chol(mat, tid);
        float ld = (tid < 128) ? logf(mat[tid*132 + tid]) : 0.f;
        red[tid] = ld; __syncthreads();
        for (int s = 128; s; s >>= 1) { if (tid < s) red[tid] += red[tid+s]; __syncthreads(); }
        if (tid == 0) scalars[0] = red[0];
        dev_dinv(mat, dinvb, tid);
        for (int e = tid; e < 16384; e += 256) Lg[e] = mat[(e>>7)*132 + (e&127)];
        for (int e = tid; e < 2048; e += 256) Dinvg[e] = dinvb[e];
    } else {
        float* rmst = shm;
        float* rkst = shm + 8192;
        float (*pacc)[64][4] = (float(*)[64][4])(shm + 16384);
        int w = tid >> 6, l = tid & 63, lm = l & 15, lg = l >> 4;
        int b = blockIdx.x - 1;
        int tile = b & 63, nq = b >> 6;
        int mt = tile >> 3, kt = tile & 7;
        int ng0 = nq * 512;
        for (int e = tid; e < 4096; e += 256) {
            int n = e >> 3, part = e & 7;
            int col = (part < 4) ? (mt*16 + part*4) : (kt*16 + (part-4)*4);
            float4 v = *(const float4*)(r_g + (size_t)(ng0 + n)*MM + col);
            float* dst = (part < 4) ? &rmst[n*16 + part*4] : &rkst[n*16 + (part-4)*4];
            *(float4*)dst = v;
        }
        half8 Bf = ((const half8*)Zh)[(kt*16 + lm)*4 + lg];
        half8 Zm = ((const half8*)Zh)[(mt*16 + lm)*4 + lg];
        f32x4 z4; z4[0]=0.f; z4[1]=0.f; z4[2]=0.f; z4[3]=0.f;
        f32x4 acc = z4;
        __syncthreads();
        int nb = w*128;
        #pragma unroll 2
        for (int i = 0; i < 128; ++i) {
            int n = nb + i;
            half8 bf = ((const half8*)bh)[(size_t)(ng0 + n)*4 + lg];
            half8 A = Zm * bf;
            f32x4 rm = *(const f32x4*)&rmst[n*16 + lg*4];
            float rk = rkst[n*16 + lm];
            f32x4 p = __builtin_amdgcn_mfma_f32_16x16x32_f16(A, Bf, z4, 0, 0, 0);
            acc[0] += fexp2(p[0] + rm[0] + rk);
            acc[1] += fexp2(p[1] + rm[1] + rk);
            acc[2] += fexp2(p[2] + rm[2] + rk);
            acc[3] += fexp2(p[3] + rm[3] + rk);
        }
        #pragma unroll
        for (int j = 0; j < 4; ++j) pacc[w][l][j] = acc[j];
        __syncthreads();
        {
            int ll = tid >> 2, j = tid & 3;
            float s = pacc[0][ll][j] + pacc[1][ll][j] + pacc[2][ll][j] + pacc[3][ll][j];
            int row = mt*16 + (ll >> 4)*4 + j;
            int col = kt*16 + (ll & 15);
            atomicAdd(&psi2[row*MM + col], s);
        }
    }
}

// ============ K4: block0 = chol(G)+Y-solve; blocks 1-16 = trace; elect final ============
__global__ __launch_bounds__(256) void cholG_kernel(
    const float* __restrict__ Kuu, const float* __restrict__ psi2,
    const float* __restrict__ Yg, const float* __restrict__ Lg,
    const float* __restrict__ Dinvg, const float* __restrict__ varp,
    const float* __restrict__ sumsP,
    float* __restrict__ scalars, int* __restrict__ cnt, float* __restrict__ out)
{
    __shared__ float mat[128*132];
    __shared__ float dinvb[8*256];
    __shared__ float rhs[128*8];
    __shared__ float tmp[128];
    __shared__ float red[256];
    int tid = threadIdx.x;
    if (blockIdx.x == 0) {
        for (int e = tid; e < 16384; e += 256)
            mat[(e>>7)*132 + (e&127)] = Kuu[e] + (1.0f/SIG2)*psi2[e];
        __syncthreads();
        dev_chol(mat, tid);
        float ld = (tid < 128) ? logf(mat[tid*132 + tid]) : 0.f;
        red[tid] = ld; __syncthreads();
        for (int s = 128; s; s >>= 1) { if (tid < s) red[tid] += red[tid+s]; __syncthreads(); }
        if (tid == 0) scalars[1] = red[0];
        dev_dinv(mat, dinvb, tid);
        if (tid < 256) { rhs[tid] = Yg[tid]; rhs[tid+256] = Yg[tid+256]; }
        __syncthreads();
        dev_solve<4>(mat, dinvb, tmp, rhs, tid);
        float c2 = rhs[tid]*rhs[tid] + rhs[tid+256]*rhs[tid+256];
        red[tid] = c2; __syncthreads();
        for (int s = 128; s; s >>= 1) { if (tid < s) red[tid] += red[tid+s]; __syncthreads(); }
        if (tid == 0) scalars[2] = red[0];
    } else {
        int c0 = (blockIdx.x - 1) * 8;
        for (int e = tid; e < 16384; e += 256) mat[(e>>7)*132 + (e&127)] = Lg[e];
        for (int e = tid; e < 2048; e += 256) dinvb[e] = Dinvg[e];
        for (int e = tid; e < 1024; e += 256) {
            int i = e >> 3, cc = e & 7;
            rhs[e] = (i == c0 + cc) ? 1.0f : 0.0f;
        }
        __syncthreads();
        dev_bsolve<8>(mat, dinvb, tmp, rhs, tid);
        int i = tid & 127, cp = tid >> 7;
        float vv0=0.f, vv1=0.f, vv2=0.f, vv3=0.f;
        for (int j = 0; j < 128; ++j) {
            float pj = psi2[i*MM + j];
            vv0 = fmaf(pj, rhs[j*8 + cp*4 + 0], vv0);
            vv1 = fmaf(pj, rhs[j*8 + cp*4 + 1], vv1);
            vv2 = fmaf(pj, rhs[j*8 + cp*4 + 2], vv2);
            vv3 = fmaf(pj, rhs[j*8 + cp*4 + 3], vv3);
        }
        float part = rhs[i*8 + cp*4 + 0]*vv0 + rhs[i*8 + cp*4 + 1]*vv1
                   + rhs[i*8 + cp*4 + 2]*vv2 + rhs[i*8 + cp*4 + 3]*vv3;
        red[tid] = part; __syncthreads();
        for (int s = 128; s; s >>= 1) { if (tid < s) red[tid] += red[tid+s]; __syncthreads(); }
        if (tid == 0) atomicAdd(&scalars[3], red[0]);
    }
    if (tid == 0) {
        __threadfence();
        int old = atomicAdd(cnt, 1);
        if (old == 16) {
            float ldK  = scalars[0];
            float ldG  = atomicAdd(&scalars[1], 0.0f);
            float c2s  = atomicAdd(&scalars[2], 0.0f);
            float trr  = atomicAdd(&scalars[3], 0.0f);
            float s1=0.f, s2=0.f, s3=0.f;
            for (int b2 = 0; b2 < 16; ++b2) {
                s1 += sumsP[b2*3+0]; s2 += sumsP[b2*3+1]; s3 += sumsP[b2*3+2];
            }
            float var = varp[0];
            float trAAT   = trr / SIG2;
            float logdetB = 2.0f * (ldG - ldK);
            float sumc2   = c2s / (SIG2*SIG2);
            float psi0    = (float)NN * var;
            const float LOG2PI = 1.837877066409345f;
            float NQf = (float)NQ;
            float bound = -0.5f*NQf*(LOG2PI + logf(SIG2));
            bound += -0.5f/SIG2 * s1;
            bound += -0.5f*(float)QQ*(psi0/SIG2 - trAAT);
            bound += -0.5f*(float)QQ*logdetB;
            bound += 0.5f*sumc2;
            bound += 0.5f*s2 + 0.5f*NQf*LOG2PI;
            bound += -(float)(LTT*QQ)*LOG2PI - 0.5f*s3;
            out[0] = bound;
        }
    }
}

extern "C" void kernel_launch(void* const* d_in, const int* in_sizes, int n_in,
                              void* d_out, int out_size, void* d_ws, size_t ws_size,
                              hipStream_t stream)
{
    (void)in_sizes; (void)n_in; (void)out_size; (void)ws_size;
    const float* Xm   = (const float*)d_in[0];
    const float* Xv   = (const float*)d_in[1];
    const float* Zg   = (const float*)d_in[2];
    const float* ls   = (const float*)d_in[3];
    const float* varp = (const float*)d_in[4];

    float* p = (float*)d_ws;
    float4*   pk4   = (float4*)p;       p += NN*DD*4;
    float*    r_g   = p;                p += NN*MM;
    _Float16* bh    = (_Float16*)p;     p += NN*DD/2;
    _Float16* Zh    = (_Float16*)p;     p += MM*DD/2;
    float*    L1p   = p;                p += NN;
    float*    bbp   = p;                p += NN;
    float*    sp    = p;                p += MM;
    float*    Kuu   = p;                p += MM*MM;
    float*    Lg    = p;                p += MM*MM;
    float*    Dinvg = p;                p += 2048;
    float*    psi2  = p;                p += MM*MM;
    float*    Yg    = p;                p += 512;
    float*    sumsP = p;                p += 64;
    float*    scalars = p;              p += 8;
    int*      cnt   = (int*)p;          p += 4;

    prepstatic_kernel<<<81, 256, 0, stream>>>(Xm, Xv, Zg, ls, varp,
                                              pk4, bh, L1p, bbp, sumsP, Kuu, sp, Zh,
                                              Yg, scalars, cnt);
    k1_kernel<<<128, 256, 0, stream>>>(Xm, Zg, pk4, L1p, bbp, sp, r_g, Yg, psi2);
    psi2chol_kernel<<<513, 256, 0, stream>>>(Zh, r_g, bh, psi2, Kuu, Lg, Dinvg, scalars);
    cholG_kernel<<<17, 256, 0, stream>>>(Kuu, psi2, Yg, Lg, Dinvg, varp, sumsP,
                                         scalars, cnt, (float*)d_out);
}